// Round 4
// baseline (8067.764 us; speedup 1.0000x reference)
//
#include <hip/hip_runtime.h>
#include <hip/hip_bf16.h>

#define NQ 8
#define NC 1024
#define ND 512
#define NROWTOT 32768
#define ROWS 32
#define BK 32
#define CP 512
#define QOFF 16777216ULL
#define TAU 0.05f

// d_out is FLOAT32: [0,16777216) quantized ; [16777216,17039360) indices ; [17039360] loss
// ws layout (floats): [0,8192) cbsq ; [8192,16384) per-block per-stage loss partials

__device__ __forceinline__ void merge_in(float &d1, int &i1, float &d2, int &i2,
                                         float nd, int ni) {
  bool b1 = (nd < d1) || (nd == d1 && ni < i1);
  bool b2 = (nd < d2) || (nd == d2 && ni < i2);
  if (b1) { d2 = d1; i2 = i1; d1 = nd; i1 = ni; }
  else if (b2) { d2 = nd; i2 = ni; }
}

__global__ __launch_bounds__(256) void cbsq_kernel(const float* __restrict__ cbg,
                                                   float* __restrict__ ws) {
  const int tid = threadIdx.x, wv = tid >> 6, lane = tid & 63;
  const int cbase = blockIdx.x * 32 + wv * 8;
  for (int j = 0; j < 8; ++j) {
    const int c = cbase + j;
    const float4* p = reinterpret_cast<const float4*>(cbg + (size_t)c * ND + lane * 8);
    float4 a = p[0], b = p[1];
    float s = a.x*a.x + a.y*a.y + a.z*a.z + a.w*a.w
            + b.x*b.x + b.y*b.y + b.z*b.z + b.w*b.w;
    #pragma unroll
    for (int m = 1; m < 64; m <<= 1) s += __shfl_xor(s, m, 64);
    if (lane == 0) ws[c] = s;
  }
}

__global__ __launch_bounds__(256, 1) void rvq_kernel(
    const float* __restrict__ emb, const float* __restrict__ cbg,
    const float* __restrict__ cbsq, float* __restrict__ lossws,
    float* __restrict__ outf) {
  __shared__ float resT[ND][ROWS];   // 64 KB, [k][row]
  __shared__ float cc[BK][CP];       // 64 KB, [k][code] (column XOR-swizzled)
  __shared__ int   idx_sh[ROWS];
  __shared__ float wred[4];

  const int tid = threadIdx.x;
  const int wv = tid >> 6, lane = tid & 63;
  const int rg = wv;        // wave's 8 rows
  const int cg = lane;      // lane's 8 codes per pass
  const int n0 = blockIdx.x * ROWS;

  // quantized accumulator: thread (r=tid&31, db=tid>>5) owns row r, dims db*64..+63
  float qacc[64];
  #pragma unroll
  for (int s = 0; s < 64; ++s) qacc[s] = 0.f;

  { // load residual = embeddings, transposed into resT
    const int r = tid & 31, db = tid >> 5;
    const float4* src = reinterpret_cast<const float4*>(emb + (size_t)(n0 + r) * ND + db * 64);
    #pragma unroll
    for (int s = 0; s < 16; ++s) {
      float4 v = src[s];
      int d = db * 64 + s * 4;
      resT[d+0][r] = v.x; resT[d+1][r] = v.y; resT[d+2][r] = v.z; resT[d+3][r] = v.w;
    }
  }
  __syncthreads();

  // lane-constant swizzled read offsets for cc
  const int c0l = cg * 8;
  const int swm = (c0l >> 6) << 2;
  const int off0 = c0l ^ swm;
  const int off1 = (c0l + 4) ^ swm;

  for (int q = 0; q < NQ; ++q) {
    const float* cbq = cbg + (size_t)q * NC * ND;
    float bd1[8], bd2[8]; int bi1[8], bi2[8];
    #pragma unroll
    for (int j = 0; j < 8; ++j) { bd1[j] = INFINITY; bd2[j] = INFINITY; bi1[j] = 0x7fffffff; bi2[j] = 0x7fffffff; }

    for (int cp = 0; cp < 2; ++cp) {
      float acc[8][8];
      #pragma unroll
      for (int a = 0; a < 8; ++a)
        #pragma unroll
        for (int b = 0; b < 8; ++b) acc[a][b] = 0.f;

      for (int kc = 0; kc < ND / BK; ++kc) {
        __syncthreads();
        { // stage codebook chunk [BK x CP] transposed + column-swizzled
          const int half = tid & 1;
          const int k0 = half * 16;
          #pragma unroll
          for (int it = 0; it < 4; ++it) {
            const int c = (tid >> 1) + it * 128;
            const int pc = c ^ ((c >> 6) << 2);
            const float4* src = reinterpret_cast<const float4*>(
                cbq + (size_t)(cp * CP + c) * ND + kc * BK + half * 16);
            float4 v0 = src[0], v1 = src[1], v2 = src[2], v3 = src[3];
            cc[k0+ 0][pc]=v0.x; cc[k0+ 1][pc]=v0.y; cc[k0+ 2][pc]=v0.z; cc[k0+ 3][pc]=v0.w;
            cc[k0+ 4][pc]=v1.x; cc[k0+ 5][pc]=v1.y; cc[k0+ 6][pc]=v1.z; cc[k0+ 7][pc]=v1.w;
            cc[k0+ 8][pc]=v2.x; cc[k0+ 9][pc]=v2.y; cc[k0+10][pc]=v2.z; cc[k0+11][pc]=v2.w;
            cc[k0+12][pc]=v3.x; cc[k0+13][pc]=v3.y; cc[k0+14][pc]=v3.z; cc[k0+15][pc]=v3.w;
          }
        }
        __syncthreads();

        float tmp[8][8];
        #pragma unroll
        for (int a = 0; a < 8; ++a)
          #pragma unroll
          for (int b = 0; b < 8; ++b) tmp[a][b] = 0.f;

        #pragma unroll
        for (int kk = 0; kk < BK; ++kk) {
          const float4* rp = reinterpret_cast<const float4*>(&resT[kc * BK + kk][rg * 8]);
          float4 r0 = rp[0], r1 = rp[1];
          const float* ccrow = &cc[kk][0];
          float4 c0 = *reinterpret_cast<const float4*>(ccrow + off0);
          float4 c1 = *reinterpret_cast<const float4*>(ccrow + off1);
          float rv[8] = {r0.x, r0.y, r0.z, r0.w, r1.x, r1.y, r1.z, r1.w};
          float cv[8] = {c0.x, c0.y, c0.z, c0.w, c1.x, c1.y, c1.z, c1.w};
          #pragma unroll
          for (int a = 0; a < 8; ++a)
            #pragma unroll
            for (int b = 0; b < 8; ++b)
              tmp[a][b] = fmaf(rv[a], cv[b], tmp[a][b]);
        }
        #pragma unroll
        for (int a = 0; a < 8; ++a)
          #pragma unroll
          for (int b = 0; b < 8; ++b) acc[a][b] += tmp[a][b];
      }

      // epilogue: dists + per-row top-2 across the wave
      const float4* qp = reinterpret_cast<const float4*>(cbsq + q * NC + cp * CP + cg * 8);
      float4 s0 = qp[0], s1 = qp[1];
      float sqv[8] = {s0.x, s0.y, s0.z, s0.w, s1.x, s1.y, s1.z, s1.w};
      #pragma unroll
      for (int r = 0; r < 8; ++r) {
        float d1 = INFINITY, d2 = INFINITY; int i1 = 0x7fffffff, i2 = 0x7fffffff;
        #pragma unroll
        for (int j = 0; j < 8; ++j) {
          float dd = sqv[j] - 2.0f * acc[r][j];
          merge_in(d1, i1, d2, i2, dd, cp * CP + cg * 8 + j);
        }
        #pragma unroll
        for (int m = 1; m < 64; m <<= 1) {
          float od1 = __shfl_xor(d1, m, 64), od2 = __shfl_xor(d2, m, 64);
          int   oi1 = __shfl_xor(i1, m, 64), oi2 = __shfl_xor(i2, m, 64);
          merge_in(d1, i1, d2, i2, od1, oi1);
          merge_in(d1, i1, d2, i2, od2, oi2);
        }
        merge_in(bd1[r], bi1[r], bd2[r], bi2[r], d1, i1);
        merge_in(bd1[r], bi1[r], bd2[r], bi2[r], d2, i2);
      }
    }

    // near-tie fp64 rescore + index write (as FLOAT32)
    #pragma unroll 1
    for (int r = 0; r < 8; ++r) {
      int fi = bi1[r];
      if (bd2[r] - bd1[r] < TAU) {
        const int row = rg * 8 + r;
        const int ia = bi1[r], ib = bi2[r];
        double da = 0.0, db2 = 0.0;
        #pragma unroll 1
        for (int t = 0; t < 2; ++t) {
          const int cidx = t ? ib : ia;
          const float* cr = cbq + (size_t)cidx * ND;
          double dot = 0.0, ss = 0.0;
          #pragma unroll
          for (int u = 0; u < 8; ++u) {
            int k = lane * 8 + u;
            double cvv = (double)cr[k];
            double rvv = (double)resT[k][row];
            dot += cvv * rvv; ss += cvv * cvv;
          }
          #pragma unroll
          for (int m = 1; m < 64; m <<= 1) { dot += __shfl_xor(dot, m, 64); ss += __shfl_xor(ss, m, 64); }
          double dd = ss - 2.0 * dot;
          if (t) db2 = dd; else da = dd;
        }
        if (db2 < da || (db2 == da && ib < ia)) fi = ib;
      }
      fi = fi < 0 ? 0 : (fi > NC - 1 ? NC - 1 : fi);
      if (lane == 0) {
        idx_sh[rg * 8 + r] = fi;
        outf[QOFF + (size_t)(n0 + rg * 8 + r) * NQ + q] = (float)fi;
      }
    }
    __syncthreads();

    { // residual update + quantized accumulation + loss partial
      const int r = tid & 31, db = tid >> 5;
      const float* crow = cbq + (size_t)idx_sh[r] * ND;
      float ls = 0.f;
      #pragma unroll
      for (int s = 0; s < 64; ++s) {
        int d = db * 64 + s;
        float cv = crow[d];
        float nv = resT[d][r] - cv;
        resT[d][r] = nv;
        qacc[s] += cv;
        ls += nv * nv;
      }
      #pragma unroll
      for (int m = 1; m < 64; m <<= 1) ls += __shfl_xor(ls, m, 64);
      if (lane == 0) wred[wv] = ls;
    }
    __syncthreads();
    if (tid == 0) lossws[blockIdx.x * NQ + q] = wred[0] + wred[1] + wred[2] + wred[3];
    __syncthreads();
  }

  // quantized store: FLOAT32, float4 per store, from registers
  {
    const int r = tid & 31, db = tid >> 5;
    #pragma unroll
    for (int g = 0; g < 16; ++g) {
      float4 w;
      w.x = qacc[g*4+0]; w.y = qacc[g*4+1]; w.z = qacc[g*4+2]; w.w = qacc[g*4+3];
      *reinterpret_cast<float4*>(outf + (size_t)(n0 + r) * ND + db * 64 + g * 4) = w;
    }
  }
}

__global__ __launch_bounds__(256) void loss_kernel(const float* __restrict__ lossws,
                                                   float* __restrict__ outf) {
  __shared__ float red[256];
  const int tid = threadIdx.x;
  float s = 0.f;
  for (int i = tid; i < 8192; i += 256) s += lossws[i];
  red[tid] = s;
  __syncthreads();
  for (int w = 128; w > 0; w >>= 1) {
    if (tid < w) red[tid] += red[tid + w];
    __syncthreads();
  }
  if (tid == 0) outf[QOFF + (size_t)NROWTOT * NQ] = red[0] / 16777216.0f;
}

extern "C" void kernel_launch(void* const* d_in, const int* in_sizes, int n_in,
                              void* d_out, int out_size, void* d_ws, size_t ws_size,
                              hipStream_t stream) {
  (void)in_sizes; (void)n_in; (void)out_size; (void)ws_size;
  const float* emb = (const float*)d_in[0];
  const float* cbg = (const float*)d_in[1];
  float* wsf = (float*)d_ws;
  float* outf = (float*)d_out;

  cbsq_kernel<<<256, 256, 0, stream>>>(cbg, wsf);
  rvq_kernel<<<1024, 256, 0, stream>>>(emb, cbg, wsf, wsf + 8192, outf);
  loss_kernel<<<1, 256, 0, stream>>>(wsf + 8192, outf);
}

// Round 5
// 5812.641 us; speedup vs baseline: 1.3880x; 1.3880x over previous
//
#include <hip/hip_runtime.h>
#include <hip/hip_bf16.h>

#define NQ 8
#define NC 1024
#define ND 512
#define NROWTOT 32768
#define QOFF 16777216ULL

typedef short short8 __attribute__((ext_vector_type(8)));
typedef float f32x16 __attribute__((ext_vector_type(16)));

__device__ __forceinline__ unsigned f2bf_u(float f) {
  unsigned u = __float_as_uint(f);
  return (u + 0x7FFFu + ((u >> 16) & 1u)) >> 16;
}
__device__ __forceinline__ unsigned pack_hl(float x) {
  unsigned hb = f2bf_u(x);
  float hf = __uint_as_float(hb << 16);
  unsigned lb = f2bf_u(x - hf);
  return (hb << 16) | lb;
}
__device__ __forceinline__ void merge_in(float &d1, int &i1, float &d2, int &i2,
                                         float nd, int ni) {
  bool b1 = (nd < d1) || (nd == d1 && ni < i1);
  bool b2 = (nd < d2) || (nd == d2 && ni < i2);
  if (b1) { d2 = d1; i2 = i1; d1 = nd; i1 = ni; }
  else if (b2) { d2 = nd; i2 = ni; }
}

__global__ __launch_bounds__(256) void cbsq_kernel(const float* __restrict__ cbg,
                                                   float* __restrict__ ws) {
  const int tid = threadIdx.x, wv = tid >> 6, lane = tid & 63;
  const int cbase = blockIdx.x * 32 + wv * 8;
  for (int j = 0; j < 8; ++j) {
    const int c = cbase + j;
    const float4* p = reinterpret_cast<const float4*>(cbg + (size_t)c * ND + lane * 8);
    float4 a = p[0], b = p[1];
    float s = a.x*a.x + a.y*a.y + a.z*a.z + a.w*a.w
            + b.x*b.x + b.y*b.y + b.z*b.z + b.w*b.w;
    #pragma unroll
    for (int m = 1; m < 64; m <<= 1) s += __shfl_xor(s, m, 64);
    if (lane == 0) ws[c] = s;
  }
}

// Split codebooks into MFMA-B-frag-ordered bf16 hi/lo, bank-swizzled.
// layout: chunk = ((q*2+cp)*32+ks), within chunk: [phys16][8k] bf16,
// i16 = grp*512 + col (grp=k-half of kstep), phys16 = i16 ^ ((i16>>3)&7)
__global__ __launch_bounds__(256) void fmt_kernel(const float* __restrict__ cbg,
                                                  unsigned short* __restrict__ Bh,
                                                  unsigned short* __restrict__ Bl) {
  int t = blockIdx.x * 256 + threadIdx.x;   // 524288 total
  int i16 = t & 1023, ks = (t >> 10) & 31, cp = (t >> 15) & 1, q = (t >> 16) & 7;
  int grp = i16 >> 9, col = i16 & 511, c = cp * 512 + col;
  const float* src = cbg + ((size_t)q * NC + c) * ND + ks * 16 + grp * 8;
  float4 a = reinterpret_cast<const float4*>(src)[0];
  float4 b = reinterpret_cast<const float4*>(src)[1];
  float v[8] = {a.x, a.y, a.z, a.w, b.x, b.y, b.z, b.w};
  unsigned short hv[8], lv[8];
  #pragma unroll
  for (int j = 0; j < 8; ++j) {
    unsigned hb = f2bf_u(v[j]);
    float hf = __uint_as_float(hb << 16);
    unsigned lb = f2bf_u(v[j] - hf);
    hv[j] = (unsigned short)hb; lv[j] = (unsigned short)lb;
  }
  int phys = i16 ^ ((i16 >> 3) & 7);
  size_t dst = (size_t)(t >> 10) * 8192 + (size_t)phys * 8;
  uint4 wh, wl;
  wh.x = hv[0] | ((unsigned)hv[1] << 16); wh.y = hv[2] | ((unsigned)hv[3] << 16);
  wh.z = hv[4] | ((unsigned)hv[5] << 16); wh.w = hv[6] | ((unsigned)hv[7] << 16);
  wl.x = lv[0] | ((unsigned)lv[1] << 16); wl.y = lv[2] | ((unsigned)lv[3] << 16);
  wl.z = lv[4] | ((unsigned)lv[5] << 16); wl.w = lv[6] | ((unsigned)lv[7] << 16);
  *reinterpret_cast<uint4*>(Bh + dst) = wh;
  *reinterpret_cast<uint4*>(Bl + dst) = wl;
}

__device__ __forceinline__ const float4* chunk_ptr(const unsigned short* Bh,
                                                   const unsigned short* Bl, int s2) {
  int q = s2 >> 7, cp = (s2 >> 6) & 1, pass = (s2 >> 5) & 1, ks = s2 & 31;
  const unsigned short* base = pass ? Bl : Bh;
  return reinterpret_cast<const float4*>(base + (size_t)((q * 2 + cp) * 32 + ks) * 8192);
}

#define ROWS64 64
#define TAU2 0.02f

__global__ __launch_bounds__(256, 1) void rvq_mfma(
    const float* __restrict__ emb, const float* __restrict__ cbg,
    const float* __restrict__ cbsq_g, float* __restrict__ lossws,
    const unsigned short* __restrict__ Bh, const unsigned short* __restrict__ Bl,
    float* __restrict__ outf) {
  __shared__ unsigned resU[ND * ROWS64];   // [k*64+row] packed hi|lo bf16, 128 KB
  __shared__ float4 Bbuf[1024];            // 16 KB staged B chunk
  __shared__ float sq_sh[NC];
  __shared__ float mrgd[2][ROWS64][2];
  __shared__ int   mrgi[2][ROWS64][2];
  __shared__ int   idx_all[NQ][ROWS64];
  __shared__ int   fi_sh[ROWS64];
  __shared__ int   tlist[ROWS64][3];
  __shared__ int   tcount;
  __shared__ float wred[4];

  const int tid = threadIdx.x;
  const int w = tid >> 6, l = tid & 63;
  const int n0 = blockIdx.x * ROWS64;
  const int rowbase = (w >> 1) * 32;
  const int colq = (w & 1) * 256;
  const int arow = rowbase + (l & 31);

  union U8 { float4 f; short8 s; unsigned u[4]; };

  { // init resU = packed(emb)
    int row = tid >> 2, kp = (tid & 3) * 128;
    const float4* src = reinterpret_cast<const float4*>(emb + (size_t)(n0 + row) * ND + kp);
    #pragma unroll 1
    for (int i = 0; i < 32; ++i) {
      float4 v = src[i];
      int k = kp + i * 4;
      resU[(k + 0) * ROWS64 + row] = pack_hl(v.x);
      resU[(k + 1) * ROWS64 + row] = pack_hl(v.y);
      resU[(k + 2) * ROWS64 + row] = pack_hl(v.z);
      resU[(k + 3) * ROWS64 + row] = pack_hl(v.w);
    }
  }

  int baddr[8];
  #pragma unroll
  for (int t = 0; t < 8; ++t) {
    int i16 = ((l >> 5) << 9) + colq + t * 32 + (l & 31);
    baddr[t] = i16 ^ ((i16 >> 3) & 7);
  }

  float4 pf0, pf1, pf2, pf3;
  {
    const float4* p = chunk_ptr(Bh, Bl, 0) + tid * 4;
    pf0 = p[0]; pf1 = p[1]; pf2 = p[2]; pf3 = p[3];
  }
  int s = 1;
  __syncthreads();

  for (int q = 0; q < NQ; ++q) {
    for (int i = tid; i < NC; i += 256) sq_sh[i] = cbsq_g[q * NC + i];
    if (tid == 0) tcount = 0;

    float bd1[16], bd2[16]; int bi1[16], bi2[16];
    #pragma unroll
    for (int r2 = 0; r2 < 16; ++r2) {
      bd1[r2] = INFINITY; bd2[r2] = INFINITY; bi1[r2] = 0x7fffffff; bi2[r2] = 0x7fffffff;
    }

    #pragma unroll 1
    for (int cp = 0; cp < 2; ++cp) {
      f32x16 acc[8];
      #pragma unroll
      for (int t = 0; t < 8; ++t)
        #pragma unroll
        for (int e = 0; e < 16; ++e) acc[t][e] = 0.f;

      #pragma unroll 1
      for (int pass = 0; pass < 2; ++pass) {
        #pragma unroll 1
        for (int ks = 0; ks < 32; ++ks) {
          __syncthreads();
          float4* bw = reinterpret_cast<float4*>(Bbuf);
          bw[tid * 4 + 0] = pf0; bw[tid * 4 + 1] = pf1;
          bw[tid * 4 + 2] = pf2; bw[tid * 4 + 3] = pf3;
          __syncthreads();
          { // prefetch next chunk (in flight under MFMAs)
            int sc = s < 1023 ? s : 1023;
            const float4* p = chunk_ptr(Bh, Bl, sc) + tid * 4;
            pf0 = p[0]; pf1 = p[1]; pf2 = p[2]; pf3 = p[3];
            ++s;
          }
          const int k0 = ks * 16 + ((l >> 5) << 3);
          unsigned ua[8];
          #pragma unroll
          for (int j = 0; j < 8; ++j) ua[j] = resU[(k0 + j) * ROWS64 + arow];
          U8 ah, al;
          #pragma unroll
          for (int p2 = 0; p2 < 4; ++p2) {
            ah.u[p2] = (ua[2*p2] >> 16) | (ua[2*p2+1] & 0xFFFF0000u);
            al.u[p2] = (ua[2*p2] & 0xFFFFu) | (ua[2*p2+1] << 16);
          }
          if (pass == 0) {
            #pragma unroll
            for (int t = 0; t < 8; ++t) {
              U8 bv; bv.f = Bbuf[baddr[t]];
              acc[t] = __builtin_amdgcn_mfma_f32_32x32x16_bf16(ah.s, bv.s, acc[t], 0, 0, 0);
              acc[t] = __builtin_amdgcn_mfma_f32_32x32x16_bf16(al.s, bv.s, acc[t], 0, 0, 0);
            }
          } else {
            #pragma unroll
            for (int t = 0; t < 8; ++t) {
              U8 bv; bv.f = Bbuf[baddr[t]];
              acc[t] = __builtin_amdgcn_mfma_f32_32x32x16_bf16(ah.s, bv.s, acc[t], 0, 0, 0);
            }
          }
        }
      }
      // epilogue for this cp: dists + per-row top2 across 32 lanes
      #pragma unroll
      for (int rg2 = 0; rg2 < 16; ++rg2) {
        float d1 = INFINITY, d2 = INFINITY; int i1 = 0x7fffffff, i2 = 0x7fffffff;
        #pragma unroll
        for (int t = 0; t < 8; ++t) {
          int col = cp * 512 + colq + t * 32 + (l & 31);
          float dd = sq_sh[col] - 2.0f * acc[t][rg2];
          merge_in(d1, i1, d2, i2, dd, col);
        }
        #pragma unroll
        for (int m = 1; m < 32; m <<= 1) {
          float od1 = __shfl_xor(d1, m, 64), od2 = __shfl_xor(d2, m, 64);
          int oi1 = __shfl_xor(i1, m, 64), oi2 = __shfl_xor(i2, m, 64);
          merge_in(d1, i1, d2, i2, od1, oi1);
          merge_in(d1, i1, d2, i2, od2, oi2);
        }
        merge_in(bd1[rg2], bi1[rg2], bd2[rg2], bi2[rg2], d1, i1);
        merge_in(bd1[rg2], bi1[rg2], bd2[rg2], bi2[rg2], d2, i2);
      }
    }

    // wave results -> LDS
    if ((l & 31) == 0) {
      int h = l >> 5;
      #pragma unroll
      for (int rg2 = 0; rg2 < 16; ++rg2) {
        int row = rowbase + (rg2 & 3) + 8 * (rg2 >> 2) + 4 * h;
        mrgd[w & 1][row][0] = bd1[rg2]; mrgd[w & 1][row][1] = bd2[rg2];
        mrgi[w & 1][row][0] = bi1[rg2]; mrgi[w & 1][row][1] = bi2[rg2];
      }
    }
    __syncthreads();

    // per-row merge + trigger list
    if (tid < ROWS64) {
      float d1 = mrgd[0][tid][0], d2 = mrgd[0][tid][1];
      int i1 = mrgi[0][tid][0], i2 = mrgi[0][tid][1];
      merge_in(d1, i1, d2, i2, mrgd[1][tid][0], mrgi[1][tid][0]);
      merge_in(d1, i1, d2, i2, mrgd[1][tid][1], mrgi[1][tid][1]);
      int fi = i1 < 0 ? 0 : (i1 > NC - 1 ? NC - 1 : i1);
      int ib = i2 < 0 ? 0 : (i2 > NC - 1 ? NC - 1 : i2);
      fi_sh[tid] = fi;
      if (d2 - d1 < TAU2 && ib != fi) {
        int p = atomicAdd(&tcount, 1);
        tlist[p][0] = tid; tlist[p][1] = fi; tlist[p][2] = ib;
      }
    }
    __syncthreads();

    // cooperative exact rescore (stepped-fp32 residual, fp64 dists)
    {
      int nt_ = tcount;
      for (int it = w; it < nt_; it += 4) {
        int row = tlist[it][0], ia = tlist[it][1], ib = tlist[it][2];
        float rr[8];
        const float4* ep = reinterpret_cast<const float4*>(emb + (size_t)(n0 + row) * ND + l * 8);
        float4 e0 = ep[0], e1 = ep[1];
        rr[0]=e0.x; rr[1]=e0.y; rr[2]=e0.z; rr[3]=e0.w;
        rr[4]=e1.x; rr[5]=e1.y; rr[6]=e1.z; rr[7]=e1.w;
        for (int t2 = 0; t2 < q; ++t2) {
          const float4* cr = reinterpret_cast<const float4*>(
              cbg + ((size_t)t2 * NC + idx_all[t2][row]) * ND + l * 8);
          float4 c0 = cr[0], c1 = cr[1];
          rr[0]-=c0.x; rr[1]-=c0.y; rr[2]-=c0.z; rr[3]-=c0.w;
          rr[4]-=c1.x; rr[5]-=c1.y; rr[6]-=c1.z; rr[7]-=c1.w;
        }
        double da = 0.0, db = 0.0;
        {
          const float4* cr = reinterpret_cast<const float4*>(
              cbg + ((size_t)q * NC + ia) * ND + l * 8);
          float4 c0 = cr[0], c1 = cr[1];
          float cv[8] = {c0.x,c0.y,c0.z,c0.w,c1.x,c1.y,c1.z,c1.w};
          #pragma unroll
          for (int j = 0; j < 8; ++j) { double e = (double)cv[j] - (double)rr[j]; da += e * e; }
        }
        {
          const float4* cr = reinterpret_cast<const float4*>(
              cbg + ((size_t)q * NC + ib) * ND + l * 8);
          float4 c0 = cr[0], c1 = cr[1];
          float cv[8] = {c0.x,c0.y,c0.z,c0.w,c1.x,c1.y,c1.z,c1.w};
          #pragma unroll
          for (int j = 0; j < 8; ++j) { double e = (double)cv[j] - (double)rr[j]; db += e * e; }
        }
        #pragma unroll
        for (int m = 1; m < 64; m <<= 1) { da += __shfl_xor(da, m, 64); db += __shfl_xor(db, m, 64); }
        if (l == 0 && (db < da || (db == da && ib < ia))) fi_sh[row] = ib;
      }
    }
    __syncthreads();

    if (tid < ROWS64) {
      idx_all[q][tid] = fi_sh[tid];
      outf[QOFF + (size_t)(n0 + tid) * NQ + q] = (float)fi_sh[tid];
    }

    // residual update + loss (+ fused quantized at last stage)
    {
      int row = tid >> 2, kp = (tid & 3) * 128;
      const float* crow = cbg + ((size_t)q * NC + fi_sh[row]) * ND;
      const float4* cp4 = reinterpret_cast<const float4*>(crow + kp);
      const float4* ep4 = reinterpret_cast<const float4*>(emb + (size_t)(n0 + row) * ND + kp);
      float4* op4 = reinterpret_cast<float4*>(outf + (size_t)(n0 + row) * ND + kp);
      float ls = 0.f;
      #pragma unroll 1
      for (int i = 0; i < 32; ++i) {
        float4 cv = cp4[i];
        int k = kp + i * 4;
        float x[4]; float cc4[4] = {cv.x, cv.y, cv.z, cv.w};
        #pragma unroll
        for (int j = 0; j < 4; ++j) {
          unsigned u = resU[(k + j) * ROWS64 + row];
          float r = __uint_as_float(u & 0xFFFF0000u) + __uint_as_float(u << 16);
          x[j] = r - cc4[j];
          resU[(k + j) * ROWS64 + row] = pack_hl(x[j]);
          ls += x[j] * x[j];
        }
        if (q == NQ - 1) {
          float4 ev = ep4[i];
          float4 qv; qv.x = ev.x - x[0]; qv.y = ev.y - x[1]; qv.z = ev.z - x[2]; qv.w = ev.w - x[3];
          op4[i] = qv;
        }
      }
      #pragma unroll
      for (int m = 1; m < 64; m <<= 1) ls += __shfl_xor(ls, m, 64);
      if (l == 0) wred[w] = ls;
    }
    __syncthreads();
    if (tid == 0) lossws[blockIdx.x * NQ + q] = wred[0] + wred[1] + wred[2] + wred[3];
  }
}

// ---------------- fallback (round-4 passing kernel) ----------------
#define ROWS 32
#define BK 32
#define CP 512
#define TAU 0.05f

__global__ __launch_bounds__(256, 1) void rvq_fb(
    const float* __restrict__ emb, const float* __restrict__ cbg,
    const float* __restrict__ cbsq, float* __restrict__ lossws,
    float* __restrict__ outf) {
  __shared__ float resT[ND][ROWS];
  __shared__ float cc[BK][CP];
  __shared__ int   idx_sh[ROWS];
  __shared__ float wred[4];

  const int tid = threadIdx.x;
  const int wv = tid >> 6, lane = tid & 63;
  const int rg = wv, cg = lane;
  const int n0 = blockIdx.x * ROWS;

  float qacc[64];
  #pragma unroll
  for (int s = 0; s < 64; ++s) qacc[s] = 0.f;

  {
    const int r = tid & 31, db = tid >> 5;
    const float4* src = reinterpret_cast<const float4*>(emb + (size_t)(n0 + r) * ND + db * 64);
    #pragma unroll
    for (int s = 0; s < 16; ++s) {
      float4 v = src[s];
      int d = db * 64 + s * 4;
      resT[d+0][r] = v.x; resT[d+1][r] = v.y; resT[d+2][r] = v.z; resT[d+3][r] = v.w;
    }
  }
  __syncthreads();

  const int c0l = cg * 8;
  const int swm = (c0l >> 6) << 2;
  const int off0 = c0l ^ swm;
  const int off1 = (c0l + 4) ^ swm;

  for (int q = 0; q < NQ; ++q) {
    const float* cbq = cbg + (size_t)q * NC * ND;
    float bd1[8], bd2[8]; int bi1[8], bi2[8];
    #pragma unroll
    for (int j = 0; j < 8; ++j) { bd1[j]=INFINITY; bd2[j]=INFINITY; bi1[j]=0x7fffffff; bi2[j]=0x7fffffff; }

    for (int cp = 0; cp < 2; ++cp) {
      float acc[8][8];
      #pragma unroll
      for (int a = 0; a < 8; ++a)
        #pragma unroll
        for (int b = 0; b < 8; ++b) acc[a][b] = 0.f;

      for (int kc = 0; kc < ND / BK; ++kc) {
        __syncthreads();
        {
          const int half = tid & 1;
          const int k0 = half * 16;
          #pragma unroll
          for (int it = 0; it < 4; ++it) {
            const int c = (tid >> 1) + it * 128;
            const int pc = c ^ ((c >> 6) << 2);
            const float4* src = reinterpret_cast<const float4*>(
                cbq + (size_t)(cp * CP + c) * ND + kc * BK + half * 16);
            float4 v0 = src[0], v1 = src[1], v2 = src[2], v3 = src[3];
            cc[k0+ 0][pc]=v0.x; cc[k0+ 1][pc]=v0.y; cc[k0+ 2][pc]=v0.z; cc[k0+ 3][pc]=v0.w;
            cc[k0+ 4][pc]=v1.x; cc[k0+ 5][pc]=v1.y; cc[k0+ 6][pc]=v1.z; cc[k0+ 7][pc]=v1.w;
            cc[k0+ 8][pc]=v2.x; cc[k0+ 9][pc]=v2.y; cc[k0+10][pc]=v2.z; cc[k0+11][pc]=v2.w;
            cc[k0+12][pc]=v3.x; cc[k0+13][pc]=v3.y; cc[k0+14][pc]=v3.z; cc[k0+15][pc]=v3.w;
          }
        }
        __syncthreads();

        float tmp[8][8];
        #pragma unroll
        for (int a = 0; a < 8; ++a)
          #pragma unroll
          for (int b = 0; b < 8; ++b) tmp[a][b] = 0.f;

        #pragma unroll
        for (int kk = 0; kk < BK; ++kk) {
          const float4* rp = reinterpret_cast<const float4*>(&resT[kc * BK + kk][rg * 8]);
          float4 r0 = rp[0], r1 = rp[1];
          const float* ccrow = &cc[kk][0];
          float4 c0 = *reinterpret_cast<const float4*>(ccrow + off0);
          float4 c1 = *reinterpret_cast<const float4*>(ccrow + off1);
          float rv[8] = {r0.x, r0.y, r0.z, r0.w, r1.x, r1.y, r1.z, r1.w};
          float cv[8] = {c0.x, c0.y, c0.z, c0.w, c1.x, c1.y, c1.z, c1.w};
          #pragma unroll
          for (int a = 0; a < 8; ++a)
            #pragma unroll
            for (int b = 0; b < 8; ++b)
              tmp[a][b] = fmaf(rv[a], cv[b], tmp[a][b]);
        }
        #pragma unroll
        for (int a = 0; a < 8; ++a)
          #pragma unroll
          for (int b = 0; b < 8; ++b) acc[a][b] += tmp[a][b];
      }

      const float4* qp = reinterpret_cast<const float4*>(cbsq + q * NC + cp * CP + cg * 8);
      float4 s0 = qp[0], s1 = qp[1];
      float sqv[8] = {s0.x, s0.y, s0.z, s0.w, s1.x, s1.y, s1.z, s1.w};
      #pragma unroll
      for (int r = 0; r < 8; ++r) {
        float d1 = INFINITY, d2 = INFINITY; int i1 = 0x7fffffff, i2 = 0x7fffffff;
        #pragma unroll
        for (int j = 0; j < 8; ++j) {
          float dd = sqv[j] - 2.0f * acc[r][j];
          merge_in(d1, i1, d2, i2, dd, cp * CP + cg * 8 + j);
        }
        #pragma unroll
        for (int m = 1; m < 64; m <<= 1) {
          float od1 = __shfl_xor(d1, m, 64), od2 = __shfl_xor(d2, m, 64);
          int oi1 = __shfl_xor(i1, m, 64), oi2 = __shfl_xor(i2, m, 64);
          merge_in(d1, i1, d2, i2, od1, oi1);
          merge_in(d1, i1, d2, i2, od2, oi2);
        }
        merge_in(bd1[r], bi1[r], bd2[r], bi2[r], d1, i1);
        merge_in(bd1[r], bi1[r], bd2[r], bi2[r], d2, i2);
      }
    }

    #pragma unroll 1
    for (int r = 0; r < 8; ++r) {
      int fi = bi1[r];
      if (bd2[r] - bd1[r] < TAU) {
        const int row = rg * 8 + r;
        const int ia = bi1[r], ib = bi2[r];
        double da = 0.0, db2 = 0.0;
        #pragma unroll 1
        for (int t = 0; t < 2; ++t) {
          const int cidx = t ? ib : ia;
          const float* cr = cbq + (size_t)cidx * ND;
          double dot = 0.0, ss = 0.0;
          #pragma unroll
          for (int u = 0; u < 8; ++u) {
            int k = lane * 8 + u;
            double cvv = (double)cr[k];
            double rvv = (double)resT[k][row];
            dot += cvv * rvv; ss += cvv * cvv;
          }
          #pragma unroll
          for (int m = 1; m < 64; m <<= 1) { dot += __shfl_xor(dot, m, 64); ss += __shfl_xor(ss, m, 64); }
          double dd = ss - 2.0 * dot;
          if (t) db2 = dd; else da = dd;
        }
        if (db2 < da || (db2 == da && ib < ia)) fi = ib;
      }
      fi = fi < 0 ? 0 : (fi > NC - 1 ? NC - 1 : fi);
      if (lane == 0) {
        idx_sh[rg * 8 + r] = fi;
        outf[QOFF + (size_t)(n0 + rg * 8 + r) * NQ + q] = (float)fi;
      }
    }
    __syncthreads();

    {
      const int r = tid & 31, db = tid >> 5;
      const float* crow = cbq + (size_t)idx_sh[r] * ND;
      float ls = 0.f;
      #pragma unroll
      for (int s = 0; s < 64; ++s) {
        int d = db * 64 + s;
        float cv = crow[d];
        float nv = resT[d][r] - cv;
        resT[d][r] = nv;
        qacc[s] += cv;
        ls += nv * nv;
      }
      #pragma unroll
      for (int m = 1; m < 64; m <<= 1) ls += __shfl_xor(ls, m, 64);
      if (lane == 0) wred[wv] = ls;
    }
    __syncthreads();
    if (tid == 0) lossws[blockIdx.x * NQ + q] = wred[0] + wred[1] + wred[2] + wred[3];
    __syncthreads();
  }

  {
    const int r = tid & 31, db = tid >> 5;
    #pragma unroll
    for (int g = 0; g < 16; ++g) {
      float4 w2;
      w2.x = qacc[g*4+0]; w2.y = qacc[g*4+1]; w2.z = qacc[g*4+2]; w2.w = qacc[g*4+3];
      *reinterpret_cast<float4*>(outf + (size_t)(n0 + r) * ND + db * 64 + g * 4) = w2;
    }
  }
}

__global__ __launch_bounds__(256) void loss_kernel(const float* __restrict__ lossws,
                                                   int n, float* __restrict__ outf) {
  __shared__ float red[256];
  const int tid = threadIdx.x;
  float s = 0.f;
  for (int i = tid; i < n; i += 256) s += lossws[i];
  red[tid] = s;
  __syncthreads();
  for (int w = 128; w > 0; w >>= 1) {
    if (tid < w) red[tid] += red[tid + w];
    __syncthreads();
  }
  if (tid == 0) outf[QOFF + (size_t)NROWTOT * NQ] = red[0] / 16777216.0f;
}

extern "C" void kernel_launch(void* const* d_in, const int* in_sizes, int n_in,
                              void* d_out, int out_size, void* d_ws, size_t ws_size,
                              hipStream_t stream) {
  (void)in_sizes; (void)n_in; (void)out_size;
  const float* emb = (const float*)d_in[0];
  const float* cbg = (const float*)d_in[1];
  float* wsf = (float*)d_ws;
  float* outf = (float*)d_out;

  cbsq_kernel<<<256, 256, 0, stream>>>(cbg, wsf);

  if (ws_size >= (size_t)18 * 1024 * 1024) {
    unsigned short* Bh = (unsigned short*)((char*)d_ws + 65536);
    unsigned short* Bl = Bh + 4194304;
    fmt_kernel<<<2048, 256, 0, stream>>>(cbg, Bh, Bl);
    rvq_mfma<<<512, 256, 0, stream>>>(emb, cbg, wsf, wsf + 8192, Bh, Bl, outf);
    loss_kernel<<<1, 256, 0, stream>>>(wsf + 8192, 4096, outf);
  } else {
    rvq_fb<<<1024, 256, 0, stream>>>(emb, cbg, wsf, wsf + 8192, outf);
    loss_kernel<<<1, 256, 0, stream>>>(wsf + 8192, 8192, outf);
  }
}

// Round 6
// 4901.568 us; speedup vs baseline: 1.6460x; 1.1859x over previous
//
#include <hip/hip_runtime.h>
#include <hip/hip_bf16.h>

#define NQ 8
#define NC 1024
#define ND 512
#define NROWTOT 32768
#define QOFF 16777216ULL

typedef short short8 __attribute__((ext_vector_type(8)));
typedef float f32x16 __attribute__((ext_vector_type(16)));

__device__ __forceinline__ unsigned f2bf_u(float f) {
  unsigned u = __float_as_uint(f);
  return (u + 0x7FFFu + ((u >> 16) & 1u)) >> 16;
}
__device__ __forceinline__ unsigned pack_hl(float x) {
  unsigned hb = f2bf_u(x);
  float hf = __uint_as_float(hb << 16);
  unsigned lb = f2bf_u(x - hf);
  return (hb << 16) | lb;
}
__device__ __forceinline__ void merge_in(float &d1, int &i1, float &d2, int &i2,
                                         float nd, int ni) {
  bool b1 = (nd < d1) || (nd == d1 && ni < i1);
  bool b2 = (nd < d2) || (nd == d2 && ni < i2);
  if (b1) { d2 = d1; i2 = i1; d1 = nd; i1 = ni; }
  else if (b2) { d2 = nd; i2 = ni; }
}

__global__ __launch_bounds__(256) void cbsq_kernel(const float* __restrict__ cbg,
                                                   float* __restrict__ ws) {
  const int tid = threadIdx.x, wv = tid >> 6, lane = tid & 63;
  const int cbase = blockIdx.x * 32 + wv * 8;
  for (int j = 0; j < 8; ++j) {
    const int c = cbase + j;
    const float4* p = reinterpret_cast<const float4*>(cbg + (size_t)c * ND + lane * 8);
    float4 a = p[0], b = p[1];
    float s = a.x*a.x + a.y*a.y + a.z*a.z + a.w*a.w
            + b.x*b.x + b.y*b.y + b.z*b.z + b.w*b.w;
    #pragma unroll
    for (int m = 1; m < 64; m <<= 1) s += __shfl_xor(s, m, 64);
    if (lane == 0) ws[c] = s;
  }
}

// Split codebooks into MFMA-B-frag-ordered bf16 hi/lo.
// chunk = (q*2+cp)*32+ks ; within chunk: [phys16][8k] bf16,
// i16 = grp*512 + col (grp = k-half of kstep), phys16 = i16 ^ ((i16>>3)&7)
__global__ __launch_bounds__(256) void fmt_kernel(const float* __restrict__ cbg,
                                                  unsigned short* __restrict__ Bh,
                                                  unsigned short* __restrict__ Bl) {
  int t = blockIdx.x * 256 + threadIdx.x;   // 524288 total
  int i16 = t & 1023, ks = (t >> 10) & 31, cp = (t >> 15) & 1, q = (t >> 16) & 7;
  int grp = i16 >> 9, col = i16 & 511, c = cp * 512 + col;
  const float* src = cbg + ((size_t)q * NC + c) * ND + ks * 16 + grp * 8;
  float4 a = reinterpret_cast<const float4*>(src)[0];
  float4 b = reinterpret_cast<const float4*>(src)[1];
  float v[8] = {a.x, a.y, a.z, a.w, b.x, b.y, b.z, b.w};
  unsigned short hv[8], lv[8];
  #pragma unroll
  for (int j = 0; j < 8; ++j) {
    unsigned hb = f2bf_u(v[j]);
    float hf = __uint_as_float(hb << 16);
    unsigned lb = f2bf_u(v[j] - hf);
    hv[j] = (unsigned short)hb; lv[j] = (unsigned short)lb;
  }
  int phys = i16 ^ ((i16 >> 3) & 7);
  size_t dst = (size_t)(t >> 10) * 8192 + (size_t)phys * 8;
  uint4 wh, wl;
  wh.x = hv[0] | ((unsigned)hv[1] << 16); wh.y = hv[2] | ((unsigned)hv[3] << 16);
  wh.z = hv[4] | ((unsigned)hv[5] << 16); wh.w = hv[6] | ((unsigned)hv[7] << 16);
  wl.x = lv[0] | ((unsigned)lv[1] << 16); wl.y = lv[2] | ((unsigned)lv[3] << 16);
  wl.z = lv[4] | ((unsigned)lv[5] << 16); wl.w = lv[6] | ((unsigned)lv[7] << 16);
  *reinterpret_cast<uint4*>(Bh + dst) = wh;
  *reinterpret_cast<uint4*>(Bl + dst) = wl;
}

#define ROWS64 64
#define TAU2 0.02f

__global__ __launch_bounds__(256, 1) void rvq_mfma(
    const float* __restrict__ emb, const float* __restrict__ cbg,
    const float* __restrict__ cbsq_g, float* __restrict__ lossws,
    const unsigned short* __restrict__ Bh, const unsigned short* __restrict__ Bl,
    float* __restrict__ outf) {
  __shared__ unsigned resU[ND * ROWS64];      // 128 KB, [k*64+row] packed hi|lo bf16
  __shared__ float mrgd[2][2][ROWS64][2];     // [cp][slot][row][top2]
  __shared__ int   mrgi[2][2][ROWS64][2];
  __shared__ int   idx_all[NQ][ROWS64];
  __shared__ int   fi_sh[ROWS64];
  __shared__ int   tlist[ROWS64][3];
  __shared__ int   tcount;
  __shared__ float wred[4];

  const int tid = threadIdx.x;
  const int w = tid >> 6, l = tid & 63;
  const int n0 = blockIdx.x * ROWS64;
  const int rowbase = (w >> 1) * 32;
  const int colq = (w & 1) * 256;
  const int arow = rowbase + (l & 31);

  union U8 { uint4 q4; short8 s; unsigned u[4]; };

  { // init resU = packed(emb); row = tid&63 -> consecutive-dword LDS (2-way free)
    const int row = tid & 63, kp = (tid >> 6) * 128;
    const float4* src = reinterpret_cast<const float4*>(emb + (size_t)(n0 + row) * ND + kp);
    #pragma unroll 1
    for (int i = 0; i < 32; ++i) {
      float4 v = src[i];
      int k = kp + i * 4;
      resU[(k + 0) * ROWS64 + row] = pack_hl(v.x);
      resU[(k + 1) * ROWS64 + row] = pack_hl(v.y);
      resU[(k + 2) * ROWS64 + row] = pack_hl(v.z);
      resU[(k + 3) * ROWS64 + row] = pack_hl(v.w);
    }
  }

  int baddr[8];   // short offsets into a chunk
  #pragma unroll
  for (int t = 0; t < 8; ++t) {
    int i16 = ((l >> 5) << 9) + colq + t * 32 + (l & 31);
    baddr[t] = (i16 ^ ((i16 >> 3) & 7)) * 8;
  }
  __syncthreads();

  for (int q = 0; q < NQ; ++q) {
    if (tid == 0) tcount = 0;   // ordered before merge-phase atomics by the post-GEMM barrier

    #pragma unroll 1
    for (int cp = 0; cp < 2; ++cp) {
      f32x16 acc[8];
      #pragma unroll
      for (int t = 0; t < 8; ++t)
        #pragma unroll
        for (int e = 0; e < 16; ++e) acc[t][e] = 0.f;

      const unsigned short* bhc = Bh + (size_t)((q * 2 + cp) * 32) * 8192;
      const unsigned short* blc = Bl + (size_t)((q * 2 + cp) * 32) * 8192;
      uint4 fA[16], fB[16];
      unsigned uaA[8], uaB[8];

#define LOADB(buf, kk) { \
      const unsigned short* _h = bhc + (size_t)(kk) * 8192; \
      const unsigned short* _l = blc + (size_t)(kk) * 8192; \
      _Pragma("unroll") \
      for (int t = 0; t < 8; ++t) { \
        buf[t]     = *reinterpret_cast<const uint4*>(_h + baddr[t]); \
        buf[8 + t] = *reinterpret_cast<const uint4*>(_l + baddr[t]); \
      } }

#define READA(ua, kk) { \
      const int _k0 = (kk) * 16 + ((l >> 5) << 3); \
      _Pragma("unroll") \
      for (int j = 0; j < 8; ++j) ua[j] = resU[(_k0 + j) * ROWS64 + arow]; }

#define MFMAS(ua, buf) { \
      U8 ah, al; \
      _Pragma("unroll") \
      for (int p2 = 0; p2 < 4; ++p2) { \
        ah.u[p2] = (ua[2*p2] >> 16) | (ua[2*p2+1] & 0xFFFF0000u); \
        al.u[p2] = (ua[2*p2] & 0xFFFFu) | (ua[2*p2+1] << 16); \
      } \
      _Pragma("unroll") \
      for (int t = 0; t < 8; ++t) { \
        U8 bh_, bl_; bh_.q4 = buf[t]; bl_.q4 = buf[8 + t]; \
        acc[t] = __builtin_amdgcn_mfma_f32_32x32x16_bf16(ah.s, bh_.s, acc[t], 0, 0, 0); \
        acc[t] = __builtin_amdgcn_mfma_f32_32x32x16_bf16(al.s, bh_.s, acc[t], 0, 0, 0); \
        acc[t] = __builtin_amdgcn_mfma_f32_32x32x16_bf16(ah.s, bl_.s, acc[t], 0, 0, 0); \
      } }

      LOADB(fA, 0); READA(uaA, 0);
      #pragma unroll 1
      for (int ks = 0; ks < 32; ks += 2) {
        LOADB(fB, ks + 1); READA(uaB, ks + 1);
        MFMAS(uaA, fA);
        const int kn = ks + 2 < 32 ? ks + 2 : 31;
        LOADB(fA, kn); READA(uaA, kn);
        MFMAS(uaB, fB);
      }
#undef LOADB
#undef READA
#undef MFMAS

      // epilogue: per-lane sq^2 loads (L2-hot) + per-row top-2 across lanes
      float sqv[8];
      #pragma unroll
      for (int t = 0; t < 8; ++t)
        sqv[t] = cbsq_g[q * NC + cp * 512 + colq + t * 32 + (l & 31)];
      #pragma unroll
      for (int rg2 = 0; rg2 < 16; ++rg2) {
        float d1 = INFINITY, d2 = INFINITY; int i1 = 0x7fffffff, i2 = 0x7fffffff;
        #pragma unroll
        for (int t = 0; t < 8; ++t) {
          int col = cp * 512 + colq + t * 32 + (l & 31);
          float dd = sqv[t] - 2.0f * acc[t][rg2];
          merge_in(d1, i1, d2, i2, dd, col);
        }
        #pragma unroll
        for (int m = 1; m < 32; m <<= 1) {
          float od1 = __shfl_xor(d1, m, 64), od2 = __shfl_xor(d2, m, 64);
          int oi1 = __shfl_xor(i1, m, 64), oi2 = __shfl_xor(i2, m, 64);
          merge_in(d1, i1, d2, i2, od1, oi1);
          merge_in(d1, i1, d2, i2, od2, oi2);
        }
        if ((l & 31) == 0) {
          int h = l >> 5;
          int row = rowbase + (rg2 & 3) + 8 * (rg2 >> 2) + 4 * h;
          mrgd[cp][w & 1][row][0] = d1; mrgd[cp][w & 1][row][1] = d2;
          mrgi[cp][w & 1][row][0] = i1; mrgi[cp][w & 1][row][1] = i2;
        }
      }
    }
    __syncthreads();

    // per-row merge of 2cp x 2slot x top2 + trigger list
    if (tid < ROWS64) {
      float d1 = INFINITY, d2 = INFINITY; int i1 = 0x7fffffff, i2 = 0x7fffffff;
      #pragma unroll
      for (int c2 = 0; c2 < 2; ++c2)
        #pragma unroll
        for (int s2 = 0; s2 < 2; ++s2) {
          merge_in(d1, i1, d2, i2, mrgd[c2][s2][tid][0], mrgi[c2][s2][tid][0]);
          merge_in(d1, i1, d2, i2, mrgd[c2][s2][tid][1], mrgi[c2][s2][tid][1]);
        }
      int fi = i1 < 0 ? 0 : (i1 > NC - 1 ? NC - 1 : i1);
      int ib = i2 < 0 ? 0 : (i2 > NC - 1 ? NC - 1 : i2);
      fi_sh[tid] = fi;
      if (d2 - d1 < TAU2 && ib != fi) {
        int p = atomicAdd(&tcount, 1);
        tlist[p][0] = tid; tlist[p][1] = fi; tlist[p][2] = ib;
      }
    }
    __syncthreads();

    // cooperative exact rescore (stepped-fp32 residual, fp64 dists)
    {
      int nt_ = tcount;
      for (int it = w; it < nt_; it += 4) {
        int row = tlist[it][0], ia = tlist[it][1], ib = tlist[it][2];
        float rr[8];
        const float4* ep = reinterpret_cast<const float4*>(emb + (size_t)(n0 + row) * ND + l * 8);
        float4 e0 = ep[0], e1 = ep[1];
        rr[0]=e0.x; rr[1]=e0.y; rr[2]=e0.z; rr[3]=e0.w;
        rr[4]=e1.x; rr[5]=e1.y; rr[6]=e1.z; rr[7]=e1.w;
        for (int t2 = 0; t2 < q; ++t2) {
          const float4* cr = reinterpret_cast<const float4*>(
              cbg + ((size_t)t2 * NC + idx_all[t2][row]) * ND + l * 8);
          float4 c0 = cr[0], c1 = cr[1];
          rr[0]-=c0.x; rr[1]-=c0.y; rr[2]-=c0.z; rr[3]-=c0.w;
          rr[4]-=c1.x; rr[5]-=c1.y; rr[6]-=c1.z; rr[7]-=c1.w;
        }
        double da = 0.0, db = 0.0;
        {
          const float4* cr = reinterpret_cast<const float4*>(
              cbg + ((size_t)q * NC + ia) * ND + l * 8);
          float4 c0 = cr[0], c1 = cr[1];
          float cv[8] = {c0.x,c0.y,c0.z,c0.w,c1.x,c1.y,c1.z,c1.w};
          #pragma unroll
          for (int j = 0; j < 8; ++j) { double e = (double)cv[j] - (double)rr[j]; da += e * e; }
        }
        {
          const float4* cr = reinterpret_cast<const float4*>(
              cbg + ((size_t)q * NC + ib) * ND + l * 8);
          float4 c0 = cr[0], c1 = cr[1];
          float cv[8] = {c0.x,c0.y,c0.z,c0.w,c1.x,c1.y,c1.z,c1.w};
          #pragma unroll
          for (int j = 0; j < 8; ++j) { double e = (double)cv[j] - (double)rr[j]; db += e * e; }
        }
        #pragma unroll
        for (int m = 1; m < 64; m <<= 1) { da += __shfl_xor(da, m, 64); db += __shfl_xor(db, m, 64); }
        if (l == 0 && (db < da || (db == da && ib < ia))) fi_sh[row] = ib;
      }
    }
    __syncthreads();

    if (tid < ROWS64) {
      idx_all[q][tid] = fi_sh[tid];
      outf[QOFF + (size_t)(n0 + tid) * NQ + q] = (float)fi_sh[tid];
    }

    // residual update + loss (+ fused quantized at last stage); row = tid&63 (2-way free)
    {
      const int row = tid & 63, kp = (tid >> 6) * 128;
      const float* crow = cbg + ((size_t)q * NC + fi_sh[row]) * ND;
      const float4* cp4 = reinterpret_cast<const float4*>(crow + kp);
      const float4* ep4 = reinterpret_cast<const float4*>(emb + (size_t)(n0 + row) * ND + kp);
      float4* op4 = reinterpret_cast<float4*>(outf + (size_t)(n0 + row) * ND + kp);
      float ls = 0.f;
      #pragma unroll 1
      for (int i = 0; i < 32; ++i) {
        float4 cv = cp4[i];
        int k = kp + i * 4;
        float x[4]; float cc4[4] = {cv.x, cv.y, cv.z, cv.w};
        #pragma unroll
        for (int j = 0; j < 4; ++j) {
          unsigned u = resU[(k + j) * ROWS64 + row];
          float r = __uint_as_float(u & 0xFFFF0000u) + __uint_as_float(u << 16);
          x[j] = r - cc4[j];
          resU[(k + j) * ROWS64 + row] = pack_hl(x[j]);
          ls += x[j] * x[j];
        }
        if (q == NQ - 1) {
          float4 ev = ep4[i];
          float4 qv; qv.x = ev.x - x[0]; qv.y = ev.y - x[1]; qv.z = ev.z - x[2]; qv.w = ev.w - x[3];
          op4[i] = qv;
        }
      }
      #pragma unroll
      for (int m = 1; m < 64; m <<= 1) ls += __shfl_xor(ls, m, 64);
      if (l == 0) wred[w] = ls;
    }
    __syncthreads();
    if (tid == 0) lossws[blockIdx.x * NQ + q] = wred[0] + wred[1] + wred[2] + wred[3];
    __syncthreads();
  }
}

// ---------------- fallback (round-4 passing kernel) ----------------
#define ROWS 32
#define BK 32
#define CP 512
#define TAU 0.05f

__global__ __launch_bounds__(256, 1) void rvq_fb(
    const float* __restrict__ emb, const float* __restrict__ cbg,
    const float* __restrict__ cbsq, float* __restrict__ lossws,
    float* __restrict__ outf) {
  __shared__ float resT[ND][ROWS];
  __shared__ float cc[BK][CP];
  __shared__ int   idx_sh[ROWS];
  __shared__ float wred[4];

  const int tid = threadIdx.x;
  const int wv = tid >> 6, lane = tid & 63;
  const int rg = wv, cg = lane;
  const int n0 = blockIdx.x * ROWS;

  float qacc[64];
  #pragma unroll
  for (int s = 0; s < 64; ++s) qacc[s] = 0.f;

  {
    const int r = tid & 31, db = tid >> 5;
    const float4* src = reinterpret_cast<const float4*>(emb + (size_t)(n0 + r) * ND + db * 64);
    #pragma unroll
    for (int s = 0; s < 16; ++s) {
      float4 v = src[s];
      int d = db * 64 + s * 4;
      resT[d+0][r] = v.x; resT[d+1][r] = v.y; resT[d+2][r] = v.z; resT[d+3][r] = v.w;
    }
  }
  __syncthreads();

  const int c0l = cg * 8;
  const int swm = (c0l >> 6) << 2;
  const int off0 = c0l ^ swm;
  const int off1 = (c0l + 4) ^ swm;

  for (int q = 0; q < NQ; ++q) {
    const float* cbq = cbg + (size_t)q * NC * ND;
    float bd1[8], bd2[8]; int bi1[8], bi2[8];
    #pragma unroll
    for (int j = 0; j < 8; ++j) { bd1[j]=INFINITY; bd2[j]=INFINITY; bi1[j]=0x7fffffff; bi2[j]=0x7fffffff; }

    for (int cp = 0; cp < 2; ++cp) {
      float acc[8][8];
      #pragma unroll
      for (int a = 0; a < 8; ++a)
        #pragma unroll
        for (int b = 0; b < 8; ++b) acc[a][b] = 0.f;

      for (int kc = 0; kc < ND / BK; ++kc) {
        __syncthreads();
        {
          const int half = tid & 1;
          const int k0 = half * 16;
          #pragma unroll
          for (int it = 0; it < 4; ++it) {
            const int c = (tid >> 1) + it * 128;
            const int pc = c ^ ((c >> 6) << 2);
            const float4* src = reinterpret_cast<const float4*>(
                cbq + (size_t)(cp * CP + c) * ND + kc * BK + half * 16);
            float4 v0 = src[0], v1 = src[1], v2 = src[2], v3 = src[3];
            cc[k0+ 0][pc]=v0.x; cc[k0+ 1][pc]=v0.y; cc[k0+ 2][pc]=v0.z; cc[k0+ 3][pc]=v0.w;
            cc[k0+ 4][pc]=v1.x; cc[k0+ 5][pc]=v1.y; cc[k0+ 6][pc]=v1.z; cc[k0+ 7][pc]=v1.w;
            cc[k0+ 8][pc]=v2.x; cc[k0+ 9][pc]=v2.y; cc[k0+10][pc]=v2.z; cc[k0+11][pc]=v2.w;
            cc[k0+12][pc]=v3.x; cc[k0+13][pc]=v3.y; cc[k0+14][pc]=v3.z; cc[k0+15][pc]=v3.w;
          }
        }
        __syncthreads();

        float tmp[8][8];
        #pragma unroll
        for (int a = 0; a < 8; ++a)
          #pragma unroll
          for (int b = 0; b < 8; ++b) tmp[a][b] = 0.f;

        #pragma unroll
        for (int kk = 0; kk < BK; ++kk) {
          const float4* rp = reinterpret_cast<const float4*>(&resT[kc * BK + kk][rg * 8]);
          float4 r0 = rp[0], r1 = rp[1];
          const float* ccrow = &cc[kk][0];
          float4 c0 = *reinterpret_cast<const float4*>(ccrow + off0);
          float4 c1 = *reinterpret_cast<const float4*>(ccrow + off1);
          float rv[8] = {r0.x, r0.y, r0.z, r0.w, r1.x, r1.y, r1.z, r1.w};
          float cv[8] = {c0.x, c0.y, c0.z, c0.w, c1.x, c1.y, c1.z, c1.w};
          #pragma unroll
          for (int a = 0; a < 8; ++a)
            #pragma unroll
            for (int b = 0; b < 8; ++b)
              tmp[a][b] = fmaf(rv[a], cv[b], tmp[a][b]);
        }
        #pragma unroll
        for (int a = 0; a < 8; ++a)
          #pragma unroll
          for (int b = 0; b < 8; ++b) acc[a][b] += tmp[a][b];
      }

      const float4* qp = reinterpret_cast<const float4*>(cbsq + q * NC + cp * CP + cg * 8);
      float4 s0 = qp[0], s1 = qp[1];
      float sqv[8] = {s0.x, s0.y, s0.z, s0.w, s1.x, s1.y, s1.z, s1.w};
      #pragma unroll
      for (int r = 0; r < 8; ++r) {
        float d1 = INFINITY, d2 = INFINITY; int i1 = 0x7fffffff, i2 = 0x7fffffff;
        #pragma unroll
        for (int j = 0; j < 8; ++j) {
          float dd = sqv[j] - 2.0f * acc[r][j];
          merge_in(d1, i1, d2, i2, dd, cp * CP + cg * 8 + j);
        }
        #pragma unroll
        for (int m = 1; m < 64; m <<= 1) {
          float od1 = __shfl_xor(d1, m, 64), od2 = __shfl_xor(d2, m, 64);
          int oi1 = __shfl_xor(i1, m, 64), oi2 = __shfl_xor(i2, m, 64);
          merge_in(d1, i1, d2, i2, od1, oi1);
          merge_in(d1, i1, d2, i2, od2, oi2);
        }
        merge_in(bd1[r], bi1[r], bd2[r], bi2[r], d1, i1);
        merge_in(bd1[r], bi1[r], bd2[r], bi2[r], d2, i2);
      }
    }

    #pragma unroll 1
    for (int r = 0; r < 8; ++r) {
      int fi = bi1[r];
      if (bd2[r] - bd1[r] < TAU) {
        const int row = rg * 8 + r;
        const int ia = bi1[r], ib = bi2[r];
        double da = 0.0, db2 = 0.0;
        #pragma unroll 1
        for (int t = 0; t < 2; ++t) {
          const int cidx = t ? ib : ia;
          const float* cr = cbq + (size_t)cidx * ND;
          double dot = 0.0, ss = 0.0;
          #pragma unroll
          for (int u = 0; u < 8; ++u) {
            int k = lane * 8 + u;
            double cvv = (double)cr[k];
            double rvv = (double)resT[k][row];
            dot += cvv * rvv; ss += cvv * cvv;
          }
          #pragma unroll
          for (int m = 1; m < 64; m <<= 1) { dot += __shfl_xor(dot, m, 64); ss += __shfl_xor(ss, m, 64); }
          double dd = ss - 2.0 * dot;
          if (t) db2 = dd; else da = dd;
        }
        if (db2 < da || (db2 == da && ib < ia)) fi = ib;
      }
      fi = fi < 0 ? 0 : (fi > NC - 1 ? NC - 1 : fi);
      if (lane == 0) {
        idx_sh[rg * 8 + r] = fi;
        outf[QOFF + (size_t)(n0 + rg * 8 + r) * NQ + q] = (float)fi;
      }
    }
    __syncthreads();

    {
      const int r = tid & 31, db = tid >> 5;
      const float* crow = cbq + (size_t)idx_sh[r] * ND;
      float ls = 0.f;
      #pragma unroll
      for (int s = 0; s < 64; ++s) {
        int d = db * 64 + s;
        float cv = crow[d];
        float nv = resT[d][r] - cv;
        resT[d][r] = nv;
        qacc[s] += cv;
        ls += nv * nv;
      }
      #pragma unroll
      for (int m = 1; m < 64; m <<= 1) ls += __shfl_xor(ls, m, 64);
      if (lane == 0) wred[wv] = ls;
    }
    __syncthreads();
    if (tid == 0) lossws[blockIdx.x * NQ + q] = wred[0] + wred[1] + wred[2] + wred[3];
    __syncthreads();
  }

  {
    const int r = tid & 31, db = tid >> 5;
    #pragma unroll
    for (int g = 0; g < 16; ++g) {
      float4 w2;
      w2.x = qacc[g*4+0]; w2.y = qacc[g*4+1]; w2.z = qacc[g*4+2]; w2.w = qacc[g*4+3];
      *reinterpret_cast<float4*>(outf + (size_t)(n0 + r) * ND + db * 64 + g * 4) = w2;
    }
  }
}

__global__ __launch_bounds__(256) void loss_kernel(const float* __restrict__ lossws,
                                                   int n, float* __restrict__ outf) {
  __shared__ float red[256];
  const int tid = threadIdx.x;
  float s = 0.f;
  for (int i = tid; i < n; i += 256) s += lossws[i];
  red[tid] = s;
  __syncthreads();
  for (int w = 128; w > 0; w >>= 1) {
    if (tid < w) red[tid] += red[tid + w];
    __syncthreads();
  }
  if (tid == 0) outf[QOFF + (size_t)NROWTOT * NQ] = red[0] / 16777216.0f;
}

extern "C" void kernel_launch(void* const* d_in, const int* in_sizes, int n_in,
                              void* d_out, int out_size, void* d_ws, size_t ws_size,
                              hipStream_t stream) {
  (void)in_sizes; (void)n_in; (void)out_size;
  const float* emb = (const float*)d_in[0];
  const float* cbg = (const float*)d_in[1];
  float* wsf = (float*)d_ws;
  float* outf = (float*)d_out;

  cbsq_kernel<<<256, 256, 0, stream>>>(cbg, wsf);

  if (ws_size >= (size_t)18 * 1024 * 1024) {
    unsigned short* Bh = (unsigned short*)((char*)d_ws + 65536);
    unsigned short* Bl = Bh + 4194304;
    fmt_kernel<<<2048, 256, 0, stream>>>(cbg, Bh, Bl);
    rvq_mfma<<<512, 256, 0, stream>>>(emb, cbg, wsf, wsf + 8192, Bh, Bl, outf);
    loss_kernel<<<1, 256, 0, stream>>>(wsf + 8192, 4096, outf);
  } else {
    rvq_fb<<<1024, 256, 0, stream>>>(emb, cbg, wsf, wsf + 8192, outf);
    loss_kernel<<<1, 256, 0, stream>>>(wsf + 8192, 8192, outf);
  }
}

// Round 7
// 4085.255 us; speedup vs baseline: 1.9748x; 1.1998x over previous
//
#include <hip/hip_runtime.h>
#include <hip/hip_bf16.h>

#define NQ 8
#define NC 1024
#define ND 512
#define NROWTOT 32768
#define QOFF 16777216ULL

typedef short short8 __attribute__((ext_vector_type(8)));
typedef float f32x16 __attribute__((ext_vector_type(16)));

__device__ __forceinline__ unsigned f2bf_u(float f) {
  unsigned u = __float_as_uint(f);
  return (u + 0x7FFFu + ((u >> 16) & 1u)) >> 16;
}
__device__ __forceinline__ unsigned pack_hl(float x) {
  unsigned hb = f2bf_u(x);
  float hf = __uint_as_float(hb << 16);
  unsigned lb = f2bf_u(x - hf);
  return (hb << 16) | lb;
}
__device__ __forceinline__ void merge_in(float &d1, int &i1, float &d2, int &i2,
                                         float nd, int ni) {
  bool b1 = (nd < d1) || (nd == d1 && ni < i1);
  bool b2 = (nd < d2) || (nd == d2 && ni < i2);
  if (b1) { d2 = d1; i2 = i1; d1 = nd; i1 = ni; }
  else if (b2) { d2 = nd; i2 = ni; }
}

__global__ __launch_bounds__(256) void cbsq_kernel(const float* __restrict__ cbg,
                                                   float* __restrict__ ws) {
  const int tid = threadIdx.x, wv = tid >> 6, lane = tid & 63;
  const int cbase = blockIdx.x * 32 + wv * 8;
  for (int j = 0; j < 8; ++j) {
    const int c = cbase + j;
    const float4* p = reinterpret_cast<const float4*>(cbg + (size_t)c * ND + lane * 8);
    float4 a = p[0], b = p[1];
    float s = a.x*a.x + a.y*a.y + a.z*a.z + a.w*a.w
            + b.x*b.x + b.y*b.y + b.z*b.z + b.w*b.w;
    #pragma unroll
    for (int m = 1; m < 64; m <<= 1) s += __shfl_xor(s, m, 64);
    if (lane == 0) ws[c] = s;
  }
}

// Split codebooks into MFMA-B-frag-ordered bf16 hi/lo.
// chunk = (q*2+cp)*32+ks ; within chunk: [phys16][8k] bf16,
// i16 = grp*512 + col (grp = k-half of kstep), phys16 = i16 ^ ((i16>>3)&7)
__global__ __launch_bounds__(256) void fmt_kernel(const float* __restrict__ cbg,
                                                  unsigned short* __restrict__ Bh,
                                                  unsigned short* __restrict__ Bl) {
  int t = blockIdx.x * 256 + threadIdx.x;   // 524288 total
  int i16 = t & 1023, ks = (t >> 10) & 31, cp = (t >> 15) & 1, q = (t >> 16) & 7;
  int grp = i16 >> 9, col = i16 & 511, c = cp * 512 + col;
  const float* src = cbg + ((size_t)q * NC + c) * ND + ks * 16 + grp * 8;
  float4 a = reinterpret_cast<const float4*>(src)[0];
  float4 b = reinterpret_cast<const float4*>(src)[1];
  float v[8] = {a.x, a.y, a.z, a.w, b.x, b.y, b.z, b.w};
  unsigned short hv[8], lv[8];
  #pragma unroll
  for (int j = 0; j < 8; ++j) {
    unsigned hb = f2bf_u(v[j]);
    float hf = __uint_as_float(hb << 16);
    unsigned lb = f2bf_u(v[j] - hf);
    hv[j] = (unsigned short)hb; lv[j] = (unsigned short)lb;
  }
  int phys = i16 ^ ((i16 >> 3) & 7);
  size_t dst = (size_t)(t >> 10) * 8192 + (size_t)phys * 8;
  uint4 wh, wl;
  wh.x = hv[0] | ((unsigned)hv[1] << 16); wh.y = hv[2] | ((unsigned)hv[3] << 16);
  wh.z = hv[4] | ((unsigned)hv[5] << 16); wh.w = hv[6] | ((unsigned)hv[7] << 16);
  wl.x = lv[0] | ((unsigned)lv[1] << 16); wl.y = lv[2] | ((unsigned)lv[3] << 16);
  wl.z = lv[4] | ((unsigned)lv[5] << 16); wl.w = lv[6] | ((unsigned)lv[7] << 16);
  *reinterpret_cast<uint4*>(Bh + dst) = wh;
  *reinterpret_cast<uint4*>(Bl + dst) = wl;
}

#define ROWS64 64
#define TAU2 0.02f

__global__ __launch_bounds__(256, 1) void rvq_mfma(
    const float* __restrict__ emb, const float* __restrict__ cbg,
    const float* __restrict__ cbsq_g, float* __restrict__ lossws,
    const unsigned short* __restrict__ Bh, const unsigned short* __restrict__ Bl,
    float* __restrict__ outf) {
  __shared__ unsigned resU[ND * ROWS64];      // 128 KB, [k*64+row] packed hi|lo bf16
  __shared__ float mrgd[2][2][ROWS64][2];     // [cp][slot][row][top2]
  __shared__ int   mrgi[2][2][ROWS64][2];
  __shared__ int   idx_all[NQ][ROWS64];
  __shared__ int   fi_sh[ROWS64];
  __shared__ int   tlist[ROWS64][3];
  __shared__ int   tcount;
  __shared__ float wred[4];

  const int tid = threadIdx.x;
  const int w = tid >> 6, l = tid & 63;
  const int n0 = blockIdx.x * ROWS64;
  const int rowbase = (w >> 1) * 32;
  const int colq = (w & 1) * 256;
  const int arow = rowbase + (l & 31);
  const int phase = blockIdx.x & 31;          // de-sync chunk walk across blocks
  const int cpswap = (blockIdx.x >> 5) & 1;   // de-sync cp order

  union U8 { uint4 q4; short8 s; unsigned u[4]; };

  { // init resU = packed(emb); row = tid&63 -> consecutive-dword LDS (2-way free)
    const int row = tid & 63, kp = (tid >> 6) * 128;
    const float4* src = reinterpret_cast<const float4*>(emb + (size_t)(n0 + row) * ND + kp);
    #pragma unroll 4
    for (int i = 0; i < 32; ++i) {
      float4 v = src[i];
      int k = kp + i * 4;
      resU[(k + 0) * ROWS64 + row] = pack_hl(v.x);
      resU[(k + 1) * ROWS64 + row] = pack_hl(v.y);
      resU[(k + 2) * ROWS64 + row] = pack_hl(v.z);
      resU[(k + 3) * ROWS64 + row] = pack_hl(v.w);
    }
  }

  int baddr[8];   // short offsets into a chunk
  #pragma unroll
  for (int t = 0; t < 8; ++t) {
    int i16 = ((l >> 5) << 9) + colq + t * 32 + (l & 31);
    baddr[t] = (i16 ^ ((i16 >> 3) & 7)) * 8;
  }
  __syncthreads();

  for (int q = 0; q < NQ; ++q) {
    if (tid == 0) tcount = 0;   // ordered before merge-phase atomics by the post-GEMM barrier

    #pragma unroll 1
    for (int cpi = 0; cpi < 2; ++cpi) {
      const int cp = cpi ^ cpswap;
      f32x16 acc[8];
      #pragma unroll
      for (int t = 0; t < 8; ++t)
        #pragma unroll
        for (int e = 0; e < 16; ++e) acc[t][e] = 0.f;

      const unsigned short* bhc = Bh + (size_t)((q * 2 + cp) * 32) * 8192;
      const unsigned short* blc = Bl + (size_t)((q * 2 + cp) * 32) * 8192;
      uint4 fA[16], fB[16];
      unsigned uaA[8], uaB[8];

      // hoist sq^2 loads: latency hidden under the whole GEMM
      float sqv[8];
      #pragma unroll
      for (int t = 0; t < 8; ++t)
        sqv[t] = cbsq_g[q * NC + cp * 512 + colq + t * 32 + (l & 31)];

#define KS(i) (((i) + phase) & 31)

#define LOADB(buf, kk) { \
      const unsigned short* _h = bhc + (size_t)(kk) * 8192; \
      const unsigned short* _l = blc + (size_t)(kk) * 8192; \
      _Pragma("unroll") \
      for (int t = 0; t < 8; ++t) { \
        buf[t]     = *reinterpret_cast<const uint4*>(_h + baddr[t]); \
        buf[8 + t] = *reinterpret_cast<const uint4*>(_l + baddr[t]); \
      } }

#define READA(ua, kk) { \
      const int _k0 = (kk) * 16 + ((l >> 5) << 3); \
      _Pragma("unroll") \
      for (int j = 0; j < 8; ++j) ua[j] = resU[(_k0 + j) * ROWS64 + arow]; }

#define MFMAS(ua, buf) { \
      U8 ah, al; \
      _Pragma("unroll") \
      for (int p2 = 0; p2 < 4; ++p2) { \
        ah.u[p2] = (ua[2*p2] >> 16) | (ua[2*p2+1] & 0xFFFF0000u); \
        al.u[p2] = (ua[2*p2] & 0xFFFFu) | (ua[2*p2+1] << 16); \
      } \
      _Pragma("unroll") \
      for (int t = 0; t < 8; ++t) { \
        U8 bh_, bl_; bh_.q4 = buf[t]; bl_.q4 = buf[8 + t]; \
        acc[t] = __builtin_amdgcn_mfma_f32_32x32x16_bf16(ah.s, bh_.s, acc[t], 0, 0, 0); \
        acc[t] = __builtin_amdgcn_mfma_f32_32x32x16_bf16(al.s, bh_.s, acc[t], 0, 0, 0); \
        acc[t] = __builtin_amdgcn_mfma_f32_32x32x16_bf16(ah.s, bl_.s, acc[t], 0, 0, 0); \
      } }

      {
        const int k00 = KS(0);
        LOADB(fA, k00); READA(uaA, k00);
      }
      #pragma unroll 1
      for (int ks = 0; ks < 32; ks += 2) {
        const int k1 = KS(ks + 1);
        LOADB(fB, k1); READA(uaB, k1);
        MFMAS(uaA, fA);
        const int kn = KS(ks + 2 < 32 ? ks + 2 : 0);   // last is a dummy (unused)
        LOADB(fA, kn); READA(uaA, kn);
        MFMAS(uaB, fB);
      }
#undef LOADB
#undef READA
#undef MFMAS
#undef KS

      // epilogue: per-row top-2 across lanes
      #pragma unroll
      for (int rg2 = 0; rg2 < 16; ++rg2) {
        float d1 = INFINITY, d2 = INFINITY; int i1 = 0x7fffffff, i2 = 0x7fffffff;
        #pragma unroll
        for (int t = 0; t < 8; ++t) {
          int col = cp * 512 + colq + t * 32 + (l & 31);
          float dd = sqv[t] - 2.0f * acc[t][rg2];
          merge_in(d1, i1, d2, i2, dd, col);
        }
        #pragma unroll
        for (int m = 1; m < 32; m <<= 1) {
          float od1 = __shfl_xor(d1, m, 64), od2 = __shfl_xor(d2, m, 64);
          int oi1 = __shfl_xor(i1, m, 64), oi2 = __shfl_xor(i2, m, 64);
          merge_in(d1, i1, d2, i2, od1, oi1);
          merge_in(d1, i1, d2, i2, od2, oi2);
        }
        if ((l & 31) == 0) {
          int h = l >> 5;
          int row = rowbase + (rg2 & 3) + 8 * (rg2 >> 2) + 4 * h;
          mrgd[cp][w & 1][row][0] = d1; mrgd[cp][w & 1][row][1] = d2;
          mrgi[cp][w & 1][row][0] = i1; mrgi[cp][w & 1][row][1] = i2;
        }
      }
    }
    __syncthreads();

    // per-row merge of 2cp x 2slot x top2 + trigger list
    if (tid < ROWS64) {
      float d1 = INFINITY, d2 = INFINITY; int i1 = 0x7fffffff, i2 = 0x7fffffff;
      #pragma unroll
      for (int c2 = 0; c2 < 2; ++c2)
        #pragma unroll
        for (int s2 = 0; s2 < 2; ++s2) {
          merge_in(d1, i1, d2, i2, mrgd[c2][s2][tid][0], mrgi[c2][s2][tid][0]);
          merge_in(d1, i1, d2, i2, mrgd[c2][s2][tid][1], mrgi[c2][s2][tid][1]);
        }
      int fi = i1 < 0 ? 0 : (i1 > NC - 1 ? NC - 1 : i1);
      int ib = i2 < 0 ? 0 : (i2 > NC - 1 ? NC - 1 : i2);
      fi_sh[tid] = fi;
      if (d2 - d1 < TAU2 && ib != fi) {
        int p = atomicAdd(&tcount, 1);
        tlist[p][0] = tid; tlist[p][1] = fi; tlist[p][2] = ib;
      }
    }
    __syncthreads();

    // cooperative exact rescore (stepped-fp32 residual, fp64 dists)
    {
      int nt_ = tcount;
      for (int it = w; it < nt_; it += 4) {
        int row = tlist[it][0], ia = tlist[it][1], ib = tlist[it][2];
        float rr[8];
        const float4* ep = reinterpret_cast<const float4*>(emb + (size_t)(n0 + row) * ND + l * 8);
        float4 e0 = ep[0], e1 = ep[1];
        rr[0]=e0.x; rr[1]=e0.y; rr[2]=e0.z; rr[3]=e0.w;
        rr[4]=e1.x; rr[5]=e1.y; rr[6]=e1.z; rr[7]=e1.w;
        for (int t2 = 0; t2 < q; ++t2) {
          const float4* cr = reinterpret_cast<const float4*>(
              cbg + ((size_t)t2 * NC + idx_all[t2][row]) * ND + l * 8);
          float4 c0 = cr[0], c1 = cr[1];
          rr[0]-=c0.x; rr[1]-=c0.y; rr[2]-=c0.z; rr[3]-=c0.w;
          rr[4]-=c1.x; rr[5]-=c1.y; rr[6]-=c1.z; rr[7]-=c1.w;
        }
        double da = 0.0, db = 0.0;
        {
          const float4* cr = reinterpret_cast<const float4*>(
              cbg + ((size_t)q * NC + ia) * ND + l * 8);
          float4 c0 = cr[0], c1 = cr[1];
          float cv[8] = {c0.x,c0.y,c0.z,c0.w,c1.x,c1.y,c1.z,c1.w};
          #pragma unroll
          for (int j = 0; j < 8; ++j) { double e = (double)cv[j] - (double)rr[j]; da += e * e; }
        }
        {
          const float4* cr = reinterpret_cast<const float4*>(
              cbg + ((size_t)q * NC + ib) * ND + l * 8);
          float4 c0 = cr[0], c1 = cr[1];
          float cv[8] = {c0.x,c0.y,c0.z,c0.w,c1.x,c1.y,c1.z,c1.w};
          #pragma unroll
          for (int j = 0; j < 8; ++j) { double e = (double)cv[j] - (double)rr[j]; db += e * e; }
        }
        #pragma unroll
        for (int m = 1; m < 64; m <<= 1) { da += __shfl_xor(da, m, 64); db += __shfl_xor(db, m, 64); }
        if (l == 0 && (db < da || (db == da && ib < ia))) fi_sh[row] = ib;
      }
    }
    __syncthreads();

    if (tid < ROWS64) {
      idx_all[q][tid] = fi_sh[tid];
      outf[QOFF + (size_t)(n0 + tid) * NQ + q] = (float)fi_sh[tid];
    }

    // residual update + loss (+ fused quantized at last stage); batched loads (8 in flight)
    {
      const int row = tid & 63, kp = (tid >> 6) * 128;
      const float* crow = cbg + ((size_t)q * NC + fi_sh[row]) * ND;
      const float4* cp4 = reinterpret_cast<const float4*>(crow + kp);
      const float4* ep4 = reinterpret_cast<const float4*>(emb + (size_t)(n0 + row) * ND + kp);
      float4* op4 = reinterpret_cast<float4*>(outf + (size_t)(n0 + row) * ND + kp);
      float ls = 0.f;
      #pragma unroll 1
      for (int i0 = 0; i0 < 32; i0 += 8) {
        float4 cv8[8], ev8[8];
        #pragma unroll
        for (int u2 = 0; u2 < 8; ++u2) cv8[u2] = cp4[i0 + u2];
        if (q == NQ - 1) {
          #pragma unroll
          for (int u2 = 0; u2 < 8; ++u2) ev8[u2] = ep4[i0 + u2];
        }
        #pragma unroll
        for (int u2 = 0; u2 < 8; ++u2) {
          const int i = i0 + u2;
          const int k = kp + i * 4;
          float x[4]; float cc4[4] = {cv8[u2].x, cv8[u2].y, cv8[u2].z, cv8[u2].w};
          #pragma unroll
          for (int j = 0; j < 4; ++j) {
            unsigned u = resU[(k + j) * ROWS64 + row];
            float r = __uint_as_float(u & 0xFFFF0000u) + __uint_as_float(u << 16);
            x[j] = r - cc4[j];
            resU[(k + j) * ROWS64 + row] = pack_hl(x[j]);
            ls += x[j] * x[j];
          }
          if (q == NQ - 1) {
            float4 qv;
            qv.x = ev8[u2].x - x[0]; qv.y = ev8[u2].y - x[1];
            qv.z = ev8[u2].z - x[2]; qv.w = ev8[u2].w - x[3];
            op4[i] = qv;
          }
        }
      }
      #pragma unroll
      for (int m = 1; m < 64; m <<= 1) ls += __shfl_xor(ls, m, 64);
      if (l == 0) wred[w] = ls;
    }
    __syncthreads();
    if (tid == 0) lossws[blockIdx.x * NQ + q] = wred[0] + wred[1] + wred[2] + wred[3];
    __syncthreads();
  }
}

// ---------------- fallback (round-4 passing kernel) ----------------
#define ROWS 32
#define BK 32
#define CP 512
#define TAU 0.05f

__global__ __launch_bounds__(256, 1) void rvq_fb(
    const float* __restrict__ emb, const float* __restrict__ cbg,
    const float* __restrict__ cbsq, float* __restrict__ lossws,
    float* __restrict__ outf) {
  __shared__ float resT[ND][ROWS];
  __shared__ float cc[BK][CP];
  __shared__ int   idx_sh[ROWS];
  __shared__ float wred[4];

  const int tid = threadIdx.x;
  const int wv = tid >> 6, lane = tid & 63;
  const int rg = wv, cg = lane;
  const int n0 = blockIdx.x * ROWS;

  float qacc[64];
  #pragma unroll
  for (int s = 0; s < 64; ++s) qacc[s] = 0.f;

  {
    const int r = tid & 31, db = tid >> 5;
    const float4* src = reinterpret_cast<const float4*>(emb + (size_t)(n0 + r) * ND + db * 64);
    #pragma unroll
    for (int s = 0; s < 16; ++s) {
      float4 v = src[s];
      int d = db * 64 + s * 4;
      resT[d+0][r] = v.x; resT[d+1][r] = v.y; resT[d+2][r] = v.z; resT[d+3][r] = v.w;
    }
  }
  __syncthreads();

  const int c0l = cg * 8;
  const int swm = (c0l >> 6) << 2;
  const int off0 = c0l ^ swm;
  const int off1 = (c0l + 4) ^ swm;

  for (int q = 0; q < NQ; ++q) {
    const float* cbq = cbg + (size_t)q * NC * ND;
    float bd1[8], bd2[8]; int bi1[8], bi2[8];
    #pragma unroll
    for (int j = 0; j < 8; ++j) { bd1[j]=INFINITY; bd2[j]=INFINITY; bi1[j]=0x7fffffff; bi2[j]=0x7fffffff; }

    for (int cp = 0; cp < 2; ++cp) {
      float acc[8][8];
      #pragma unroll
      for (int a = 0; a < 8; ++a)
        #pragma unroll
        for (int b = 0; b < 8; ++b) acc[a][b] = 0.f;

      for (int kc = 0; kc < ND / BK; ++kc) {
        __syncthreads();
        {
          const int half = tid & 1;
          const int k0 = half * 16;
          #pragma unroll
          for (int it = 0; it < 4; ++it) {
            const int c = (tid >> 1) + it * 128;
            const int pc = c ^ ((c >> 6) << 2);
            const float4* src = reinterpret_cast<const float4*>(
                cbq + (size_t)(cp * CP + c) * ND + kc * BK + half * 16);
            float4 v0 = src[0], v1 = src[1], v2 = src[2], v3 = src[3];
            cc[k0+ 0][pc]=v0.x; cc[k0+ 1][pc]=v0.y; cc[k0+ 2][pc]=v0.z; cc[k0+ 3][pc]=v0.w;
            cc[k0+ 4][pc]=v1.x; cc[k0+ 5][pc]=v1.y; cc[k0+ 6][pc]=v1.z; cc[k0+ 7][pc]=v1.w;
            cc[k0+ 8][pc]=v2.x; cc[k0+ 9][pc]=v2.y; cc[k0+10][pc]=v2.z; cc[k0+11][pc]=v2.w;
            cc[k0+12][pc]=v3.x; cc[k0+13][pc]=v3.y; cc[k0+14][pc]=v3.z; cc[k0+15][pc]=v3.w;
          }
        }
        __syncthreads();

        float tmp[8][8];
        #pragma unroll
        for (int a = 0; a < 8; ++a)
          #pragma unroll
          for (int b = 0; b < 8; ++b) tmp[a][b] = 0.f;

        #pragma unroll
        for (int kk = 0; kk < BK; ++kk) {
          const float4* rp = reinterpret_cast<const float4*>(&resT[kc * BK + kk][rg * 8]);
          float4 r0 = rp[0], r1 = rp[1];
          const float* ccrow = &cc[kk][0];
          float4 c0 = *reinterpret_cast<const float4*>(ccrow + off0);
          float4 c1 = *reinterpret_cast<const float4*>(ccrow + off1);
          float rv[8] = {r0.x, r0.y, r0.z, r0.w, r1.x, r1.y, r1.z, r1.w};
          float cv[8] = {c0.x, c0.y, c0.z, c0.w, c1.x, c1.y, c1.z, c1.w};
          #pragma unroll
          for (int a = 0; a < 8; ++a)
            #pragma unroll
            for (int b = 0; b < 8; ++b)
              tmp[a][b] = fmaf(rv[a], cv[b], tmp[a][b]);
        }
        #pragma unroll
        for (int a = 0; a < 8; ++a)
          #pragma unroll
          for (int b = 0; b < 8; ++b) acc[a][b] += tmp[a][b];
      }

      const float4* qp = reinterpret_cast<const float4*>(cbsq + q * NC + cp * CP + cg * 8);
      float4 s0 = qp[0], s1 = qp[1];
      float sqv[8] = {s0.x, s0.y, s0.z, s0.w, s1.x, s1.y, s1.z, s1.w};
      #pragma unroll
      for (int r = 0; r < 8; ++r) {
        float d1 = INFINITY, d2 = INFINITY; int i1 = 0x7fffffff, i2 = 0x7fffffff;
        #pragma unroll
        for (int j = 0; j < 8; ++j) {
          float dd = sqv[j] - 2.0f * acc[r][j];
          merge_in(d1, i1, d2, i2, dd, cp * CP + cg * 8 + j);
        }
        #pragma unroll
        for (int m = 1; m < 64; m <<= 1) {
          float od1 = __shfl_xor(d1, m, 64), od2 = __shfl_xor(d2, m, 64);
          int oi1 = __shfl_xor(i1, m, 64), oi2 = __shfl_xor(i2, m, 64);
          merge_in(d1, i1, d2, i2, od1, oi1);
          merge_in(d1, i1, d2, i2, od2, oi2);
        }
        merge_in(bd1[r], bi1[r], bd2[r], bi2[r], d1, i1);
        merge_in(bd1[r], bi1[r], bd2[r], bi2[r], d2, i2);
      }
    }

    #pragma unroll 1
    for (int r = 0; r < 8; ++r) {
      int fi = bi1[r];
      if (bd2[r] - bd1[r] < TAU) {
        const int row = rg * 8 + r;
        const int ia = bi1[r], ib = bi2[r];
        double da = 0.0, db2 = 0.0;
        #pragma unroll 1
        for (int t = 0; t < 2; ++t) {
          const int cidx = t ? ib : ia;
          const float* cr = cbq + (size_t)cidx * ND;
          double dot = 0.0, ss = 0.0;
          #pragma unroll
          for (int u = 0; u < 8; ++u) {
            int k = lane * 8 + u;
            double cvv = (double)cr[k];
            double rvv = (double)resT[k][row];
            dot += cvv * rvv; ss += cvv * cvv;
          }
          #pragma unroll
          for (int m = 1; m < 64; m <<= 1) { dot += __shfl_xor(dot, m, 64); ss += __shfl_xor(ss, m, 64); }
          double dd = ss - 2.0 * dot;
          if (t) db2 = dd; else da = dd;
        }
        if (db2 < da || (db2 == da && ib < ia)) fi = ib;
      }
      fi = fi < 0 ? 0 : (fi > NC - 1 ? NC - 1 : fi);
      if (lane == 0) {
        idx_sh[rg * 8 + r] = fi;
        outf[QOFF + (size_t)(n0 + rg * 8 + r) * NQ + q] = (float)fi;
      }
    }
    __syncthreads();

    {
      const int r = tid & 31, db = tid >> 5;
      const float* crow = cbq + (size_t)idx_sh[r] * ND;
      float ls = 0.f;
      #pragma unroll
      for (int s = 0; s < 64; ++s) {
        int d = db * 64 + s;
        float cv = crow[d];
        float nv = resT[d][r] - cv;
        resT[d][r] = nv;
        qacc[s] += cv;
        ls += nv * nv;
      }
      #pragma unroll
      for (int m = 1; m < 64; m <<= 1) ls += __shfl_xor(ls, m, 64);
      if (lane == 0) wred[wv] = ls;
    }
    __syncthreads();
    if (tid == 0) lossws[blockIdx.x * NQ + q] = wred[0] + wred[1] + wred[2] + wred[3];
    __syncthreads();
  }

  {
    const int r = tid & 31, db = tid >> 5;
    #pragma unroll
    for (int g = 0; g < 16; ++g) {
      float4 w2;
      w2.x = qacc[g*4+0]; w2.y = qacc[g*4+1]; w2.z = qacc[g*4+2]; w2.w = qacc[g*4+3];
      *reinterpret_cast<float4*>(outf + (size_t)(n0 + r) * ND + db * 64 + g * 4) = w2;
    }
  }
}

__global__ __launch_bounds__(256) void loss_kernel(const float* __restrict__ lossws,
                                                   int n, float* __restrict__ outf) {
  __shared__ float red[256];
  const int tid = threadIdx.x;
  float s = 0.f;
  for (int i = tid; i < n; i += 256) s += lossws[i];
  red[tid] = s;
  __syncthreads();
  for (int w = 128; w > 0; w >>= 1) {
    if (tid < w) red[tid] += red[tid + w];
    __syncthreads();
  }
  if (tid == 0) outf[QOFF + (size_t)NROWTOT * NQ] = red[0] / 16777216.0f;
}

extern "C" void kernel_launch(void* const* d_in, const int* in_sizes, int n_in,
                              void* d_out, int out_size, void* d_ws, size_t ws_size,
                              hipStream_t stream) {
  (void)in_sizes; (void)n_in; (void)out_size;
  const float* emb = (const float*)d_in[0];
  const float* cbg = (const float*)d_in[1];
  float* wsf = (float*)d_ws;
  float* outf = (float*)d_out;

  cbsq_kernel<<<256, 256, 0, stream>>>(cbg, wsf);

  if (ws_size >= (size_t)18 * 1024 * 1024) {
    unsigned short* Bh = (unsigned short*)((char*)d_ws + 65536);
    unsigned short* Bl = Bh + 4194304;
    fmt_kernel<<<2048, 256, 0, stream>>>(cbg, Bh, Bl);
    rvq_mfma<<<512, 256, 0, stream>>>(emb, cbg, wsf, wsf + 8192, Bh, Bl, outf);
    loss_kernel<<<1, 256, 0, stream>>>(wsf + 8192, 4096, outf);
  } else {
    rvq_fb<<<1024, 256, 0, stream>>>(emb, cbg, wsf, wsf + 8192, outf);
    loss_kernel<<<1, 256, 0, stream>>>(wsf + 8192, 8192, outf);
  }
}

// Round 8
// 3943.005 us; speedup vs baseline: 2.0461x; 1.0361x over previous
//
#include <hip/hip_runtime.h>
#include <hip/hip_bf16.h>

#define NQ 8
#define NC 1024
#define ND 512
#define NROWTOT 32768
#define QOFF 16777216ULL

typedef short short8 __attribute__((ext_vector_type(8)));
typedef float f32x16 __attribute__((ext_vector_type(16)));

__device__ __forceinline__ unsigned f2bf_u(float f) {
  unsigned u = __float_as_uint(f);
  return (u + 0x7FFFu + ((u >> 16) & 1u)) >> 16;
}
__device__ __forceinline__ unsigned pack_hl(float x) {
  unsigned hb = f2bf_u(x);
  float hf = __uint_as_float(hb << 16);
  unsigned lb = f2bf_u(x - hf);
  return (hb << 16) | lb;
}
__device__ __forceinline__ void merge_in(float &d1, int &i1, float &d2, int &i2,
                                         float nd, int ni) {
  bool b1 = (nd < d1) || (nd == d1 && ni < i1);
  bool b2 = (nd < d2) || (nd == d2 && ni < i2);
  if (b1) { d2 = d1; i2 = i1; d1 = nd; i1 = ni; }
  else if (b2) { d2 = nd; i2 = ni; }
}

__global__ __launch_bounds__(256) void cbsq_kernel(const float* __restrict__ cbg,
                                                   float* __restrict__ ws) {
  const int tid = threadIdx.x, wv = tid >> 6, lane = tid & 63;
  const int cbase = blockIdx.x * 32 + wv * 8;
  for (int j = 0; j < 8; ++j) {
    const int c = cbase + j;
    const float4* p = reinterpret_cast<const float4*>(cbg + (size_t)c * ND + lane * 8);
    float4 a = p[0], b = p[1];
    float s = a.x*a.x + a.y*a.y + a.z*a.z + a.w*a.w
            + b.x*b.x + b.y*b.y + b.z*b.z + b.w*b.w;
    #pragma unroll
    for (int m = 1; m < 64; m <<= 1) s += __shfl_xor(s, m, 64);
    if (lane == 0) ws[c] = s;
  }
}

// Split codebooks into MFMA-B-frag-ordered bf16 hi/lo.
// chunk = (q*2+cp)*32+ks ; within chunk: [phys16][8k] bf16,
// i16 = grp*512 + col (grp = k-half of kstep), phys16 = i16 ^ ((i16>>3)&7)
__global__ __launch_bounds__(256) void fmt_kernel(const float* __restrict__ cbg,
                                                  unsigned short* __restrict__ Bh,
                                                  unsigned short* __restrict__ Bl) {
  int t = blockIdx.x * 256 + threadIdx.x;   // 524288 total
  int i16 = t & 1023, ks = (t >> 10) & 31, cp = (t >> 15) & 1, q = (t >> 16) & 7;
  int grp = i16 >> 9, col = i16 & 511, c = cp * 512 + col;
  const float* src = cbg + ((size_t)q * NC + c) * ND + ks * 16 + grp * 8;
  float4 a = reinterpret_cast<const float4*>(src)[0];
  float4 b = reinterpret_cast<const float4*>(src)[1];
  float v[8] = {a.x, a.y, a.z, a.w, b.x, b.y, b.z, b.w};
  unsigned short hv[8], lv[8];
  #pragma unroll
  for (int j = 0; j < 8; ++j) {
    unsigned hb = f2bf_u(v[j]);
    float hf = __uint_as_float(hb << 16);
    unsigned lb = f2bf_u(v[j] - hf);
    hv[j] = (unsigned short)hb; lv[j] = (unsigned short)lb;
  }
  int phys = i16 ^ ((i16 >> 3) & 7);
  size_t dst = (size_t)(t >> 10) * 8192 + (size_t)phys * 8;
  uint4 wh, wl;
  wh.x = hv[0] | ((unsigned)hv[1] << 16); wh.y = hv[2] | ((unsigned)hv[3] << 16);
  wh.z = hv[4] | ((unsigned)hv[5] << 16); wh.w = hv[6] | ((unsigned)hv[7] << 16);
  wl.x = lv[0] | ((unsigned)lv[1] << 16); wl.y = lv[2] | ((unsigned)lv[3] << 16);
  wl.z = lv[4] | ((unsigned)lv[5] << 16); wl.w = lv[6] | ((unsigned)lv[7] << 16);
  *reinterpret_cast<uint4*>(Bh + dst) = wh;
  *reinterpret_cast<uint4*>(Bl + dst) = wl;
}

#define ROWS64 64
#define TAU2 0.02f

// 1024 threads = 16 waves: 2 rowgroups x 8 colgroups (64 cols each).
// Per wave: acc[2] tiles, 4 B-loads + 8 A-ds_reads + 6 MFMA per k-step.
__global__ __launch_bounds__(1024, 4) void rvq_mfma(
    const float* __restrict__ emb, const float* __restrict__ cbg,
    const float* __restrict__ cbsq_g, float* __restrict__ lossws,
    const unsigned short* __restrict__ Bh, const unsigned short* __restrict__ Bl,
    float* __restrict__ outf) {
  __shared__ unsigned resU[ND * ROWS64];      // 128 KB, [k*64+row] packed hi|lo bf16
  __shared__ float mrgd[2][8][ROWS64][2];     // [cp][colgroup][row][top2] 8 KB
  __shared__ int   mrgi[2][8][ROWS64][2];     // 8 KB
  __shared__ int   idx_all[NQ][ROWS64];
  __shared__ int   fi_sh[ROWS64];
  __shared__ int   tlist[ROWS64][3];
  __shared__ int   tcount;
  __shared__ float wred[16];

  const int tid = threadIdx.x;
  const int w = tid >> 6, l = tid & 63;
  const int n0 = blockIdx.x * ROWS64;
  const int rowbase = (w >> 3) * 32;          // 2 rowgroups
  const int colq = (w & 7) * 64;              // 8 colgroups of 64 cols
  const int arow = rowbase + (l & 31);
  const int phase = blockIdx.x & 31;          // de-sync chunk walk across blocks
  const int cpswap = (blockIdx.x >> 5) & 1;   // de-sync cp order

  union U8 { uint4 q4; short8 s; unsigned u[4]; };

  { // init resU = packed(emb); 16 threads/row, 32 dims each
    const int row = tid & 63, kp = (tid >> 6) * 32;
    const float4* src = reinterpret_cast<const float4*>(emb + (size_t)(n0 + row) * ND + kp);
    float4 v8[8];
    #pragma unroll
    for (int i = 0; i < 8; ++i) v8[i] = src[i];
    #pragma unroll
    for (int i = 0; i < 8; ++i) {
      int k = kp + i * 4;
      resU[(k + 0) * ROWS64 + row] = pack_hl(v8[i].x);
      resU[(k + 1) * ROWS64 + row] = pack_hl(v8[i].y);
      resU[(k + 2) * ROWS64 + row] = pack_hl(v8[i].z);
      resU[(k + 3) * ROWS64 + row] = pack_hl(v8[i].w);
    }
  }

  int baddr[2];   // short offsets into a chunk, per tile
  #pragma unroll
  for (int t = 0; t < 2; ++t) {
    int i16 = ((l >> 5) << 9) + colq + t * 32 + (l & 31);
    baddr[t] = (i16 ^ ((i16 >> 3) & 7)) * 8;
  }
  __syncthreads();

  for (int q = 0; q < NQ; ++q) {
    if (tid == 0) tcount = 0;   // ordered before merge-phase atomics by the post-GEMM barrier

    #pragma unroll 1
    for (int cpi = 0; cpi < 2; ++cpi) {
      const int cp = cpi ^ cpswap;
      f32x16 acc[2];
      #pragma unroll
      for (int t = 0; t < 2; ++t)
        #pragma unroll
        for (int e = 0; e < 16; ++e) acc[t][e] = 0.f;

      const unsigned short* bhc = Bh + (size_t)((q * 2 + cp) * 32) * 8192;
      const unsigned short* blc = Bl + (size_t)((q * 2 + cp) * 32) * 8192;
      uint4 fA[4], fB[4];
      unsigned uaA[8], uaB[8];

      // hoist sq^2 loads: latency hidden under the whole GEMM
      float sqv[2];
      #pragma unroll
      for (int t = 0; t < 2; ++t)
        sqv[t] = cbsq_g[q * NC + cp * 512 + colq + t * 32 + (l & 31)];

#define KS(i) (((i) + phase) & 31)

#define LOADB(buf, kk) { \
      const unsigned short* _h = bhc + (size_t)(kk) * 8192; \
      const unsigned short* _l = blc + (size_t)(kk) * 8192; \
      _Pragma("unroll") \
      for (int t = 0; t < 2; ++t) { \
        buf[t]     = *reinterpret_cast<const uint4*>(_h + baddr[t]); \
        buf[2 + t] = *reinterpret_cast<const uint4*>(_l + baddr[t]); \
      } }

#define READA(ua, kk) { \
      const int _k0 = (kk) * 16 + ((l >> 5) << 3); \
      _Pragma("unroll") \
      for (int j = 0; j < 8; ++j) ua[j] = resU[(_k0 + j) * ROWS64 + arow]; }

#define MFMAS(ua, buf) { \
      U8 ah, al; \
      _Pragma("unroll") \
      for (int p2 = 0; p2 < 4; ++p2) { \
        ah.u[p2] = (ua[2*p2] >> 16) | (ua[2*p2+1] & 0xFFFF0000u); \
        al.u[p2] = (ua[2*p2] & 0xFFFFu) | (ua[2*p2+1] << 16); \
      } \
      _Pragma("unroll") \
      for (int t = 0; t < 2; ++t) { \
        U8 bh_, bl_; bh_.q4 = buf[t]; bl_.q4 = buf[2 + t]; \
        acc[t] = __builtin_amdgcn_mfma_f32_32x32x16_bf16(ah.s, bh_.s, acc[t], 0, 0, 0); \
        acc[t] = __builtin_amdgcn_mfma_f32_32x32x16_bf16(al.s, bh_.s, acc[t], 0, 0, 0); \
        acc[t] = __builtin_amdgcn_mfma_f32_32x32x16_bf16(ah.s, bl_.s, acc[t], 0, 0, 0); \
      } }

      {
        const int k00 = KS(0);
        LOADB(fA, k00); READA(uaA, k00);
      }
      #pragma unroll 1
      for (int ks = 0; ks < 32; ks += 2) {
        const int k1 = KS(ks + 1);
        LOADB(fB, k1); READA(uaB, k1);
        MFMAS(uaA, fA);
        const int kn = KS(ks + 2 < 32 ? ks + 2 : 0);   // last is a dummy (unused)
        LOADB(fA, kn); READA(uaA, kn);
        MFMAS(uaB, fB);
      }
#undef LOADB
#undef READA
#undef MFMAS
#undef KS

      // epilogue: per-row top-2 across this wave's 64 cols
      #pragma unroll
      for (int rg2 = 0; rg2 < 16; ++rg2) {
        float d1 = INFINITY, d2 = INFINITY; int i1 = 0x7fffffff, i2 = 0x7fffffff;
        #pragma unroll
        for (int t = 0; t < 2; ++t) {
          int col = cp * 512 + colq + t * 32 + (l & 31);
          float dd = sqv[t] - 2.0f * acc[t][rg2];
          merge_in(d1, i1, d2, i2, dd, col);
        }
        #pragma unroll
        for (int m = 1; m < 32; m <<= 1) {
          float od1 = __shfl_xor(d1, m, 64), od2 = __shfl_xor(d2, m, 64);
          int oi1 = __shfl_xor(i1, m, 64), oi2 = __shfl_xor(i2, m, 64);
          merge_in(d1, i1, d2, i2, od1, oi1);
          merge_in(d1, i1, d2, i2, od2, oi2);
        }
        if ((l & 31) == 0) {
          int h = l >> 5;
          int row = rowbase + (rg2 & 3) + 8 * (rg2 >> 2) + 4 * h;
          mrgd[cp][w & 7][row][0] = d1; mrgd[cp][w & 7][row][1] = d2;
          mrgi[cp][w & 7][row][0] = i1; mrgi[cp][w & 7][row][1] = i2;
        }
      }
    }
    __syncthreads();

    // per-row merge of 2cp x 8 colgroups x top2 + trigger list
    if (tid < ROWS64) {
      float d1 = INFINITY, d2 = INFINITY; int i1 = 0x7fffffff, i2 = 0x7fffffff;
      #pragma unroll
      for (int c2 = 0; c2 < 2; ++c2)
        #pragma unroll
        for (int s2 = 0; s2 < 8; ++s2) {
          merge_in(d1, i1, d2, i2, mrgd[c2][s2][tid][0], mrgi[c2][s2][tid][0]);
          merge_in(d1, i1, d2, i2, mrgd[c2][s2][tid][1], mrgi[c2][s2][tid][1]);
        }
      int fi = i1 < 0 ? 0 : (i1 > NC - 1 ? NC - 1 : i1);
      int ib = i2 < 0 ? 0 : (i2 > NC - 1 ? NC - 1 : i2);
      fi_sh[tid] = fi;
      if (d2 - d1 < TAU2 && ib != fi) {
        int p = atomicAdd(&tcount, 1);
        tlist[p][0] = tid; tlist[p][1] = fi; tlist[p][2] = ib;
      }
    }
    __syncthreads();

    // cooperative exact rescore (stepped-fp32 residual, fp64 dists)
    {
      int nt_ = tcount;
      for (int it = w; it < nt_; it += 16) {
        int row = tlist[it][0], ia = tlist[it][1], ib = tlist[it][2];
        float rr[8];
        const float4* ep = reinterpret_cast<const float4*>(emb + (size_t)(n0 + row) * ND + l * 8);
        float4 e0 = ep[0], e1 = ep[1];
        rr[0]=e0.x; rr[1]=e0.y; rr[2]=e0.z; rr[3]=e0.w;
        rr[4]=e1.x; rr[5]=e1.y; rr[6]=e1.z; rr[7]=e1.w;
        for (int t2 = 0; t2 < q; ++t2) {
          const float4* cr = reinterpret_cast<const float4*>(
              cbg + ((size_t)t2 * NC + idx_all[t2][row]) * ND + l * 8);
          float4 c0 = cr[0], c1 = cr[1];
          rr[0]-=c0.x; rr[1]-=c0.y; rr[2]-=c0.z; rr[3]-=c0.w;
          rr[4]-=c1.x; rr[5]-=c1.y; rr[6]-=c1.z; rr[7]-=c1.w;
        }
        double da = 0.0, db = 0.0;
        {
          const float4* cr = reinterpret_cast<const float4*>(
              cbg + ((size_t)q * NC + ia) * ND + l * 8);
          float4 c0 = cr[0], c1 = cr[1];
          float cv[8] = {c0.x,c0.y,c0.z,c0.w,c1.x,c1.y,c1.z,c1.w};
          #pragma unroll
          for (int j = 0; j < 8; ++j) { double e = (double)cv[j] - (double)rr[j]; da += e * e; }
        }
        {
          const float4* cr = reinterpret_cast<const float4*>(
              cbg + ((size_t)q * NC + ib) * ND + l * 8);
          float4 c0 = cr[0], c1 = cr[1];
          float cv[8] = {c0.x,c0.y,c0.z,c0.w,c1.x,c1.y,c1.z,c1.w};
          #pragma unroll
          for (int j = 0; j < 8; ++j) { double e = (double)cv[j] - (double)rr[j]; db += e * e; }
        }
        #pragma unroll
        for (int m = 1; m < 64; m <<= 1) { da += __shfl_xor(da, m, 64); db += __shfl_xor(db, m, 64); }
        if (l == 0 && (db < da || (db == da && ib < ia))) fi_sh[row] = ib;
      }
    }
    __syncthreads();

    if (tid < ROWS64) {
      idx_all[q][tid] = fi_sh[tid];
      outf[QOFF + (size_t)(n0 + tid) * NQ + q] = (float)fi_sh[tid];
    }

    // residual update + loss (+ fused quantized at last stage); 16 threads/row, 32 dims
    {
      const int row = tid & 63, kp = (tid >> 6) * 32;
      const float* crow = cbg + ((size_t)q * NC + fi_sh[row]) * ND;
      const float4* cp4 = reinterpret_cast<const float4*>(crow + kp);
      const float4* ep4 = reinterpret_cast<const float4*>(emb + (size_t)(n0 + row) * ND + kp);
      float4* op4 = reinterpret_cast<float4*>(outf + (size_t)(n0 + row) * ND + kp);
      float ls = 0.f;
      float4 cv8[8], ev8[8];
      #pragma unroll
      for (int u2 = 0; u2 < 8; ++u2) cv8[u2] = cp4[u2];
      if (q == NQ - 1) {
        #pragma unroll
        for (int u2 = 0; u2 < 8; ++u2) ev8[u2] = ep4[u2];
      }
      #pragma unroll
      for (int u2 = 0; u2 < 8; ++u2) {
        const int k = kp + u2 * 4;
        float x[4]; float cc4[4] = {cv8[u2].x, cv8[u2].y, cv8[u2].z, cv8[u2].w};
        #pragma unroll
        for (int j = 0; j < 4; ++j) {
          unsigned u = resU[(k + j) * ROWS64 + row];
          float r = __uint_as_float(u & 0xFFFF0000u) + __uint_as_float(u << 16);
          x[j] = r - cc4[j];
          resU[(k + j) * ROWS64 + row] = pack_hl(x[j]);
          ls += x[j] * x[j];
        }
        if (q == NQ - 1) {
          float4 qv;
          qv.x = ev8[u2].x - x[0]; qv.y = ev8[u2].y - x[1];
          qv.z = ev8[u2].z - x[2]; qv.w = ev8[u2].w - x[3];
          op4[u2] = qv;
        }
      }
      #pragma unroll
      for (int m = 1; m < 64; m <<= 1) ls += __shfl_xor(ls, m, 64);
      if (l == 0) wred[w] = ls;
    }
    __syncthreads();
    if (tid == 0) {
      float s = 0.f;
      #pragma unroll
      for (int i = 0; i < 16; ++i) s += wred[i];
      lossws[blockIdx.x * NQ + q] = s;
    }
    __syncthreads();
  }
}

// ---------------- fallback (round-4 passing kernel) ----------------
#define ROWS 32
#define BK 32
#define CP 512
#define TAU 0.05f

__global__ __launch_bounds__(256, 1) void rvq_fb(
    const float* __restrict__ emb, const float* __restrict__ cbg,
    const float* __restrict__ cbsq, float* __restrict__ lossws,
    float* __restrict__ outf) {
  __shared__ float resT[ND][ROWS];
  __shared__ float cc[BK][CP];
  __shared__ int   idx_sh[ROWS];
  __shared__ float wred[4];

  const int tid = threadIdx.x;
  const int wv = tid >> 6, lane = tid & 63;
  const int rg = wv, cg = lane;
  const int n0 = blockIdx.x * ROWS;

  float qacc[64];
  #pragma unroll
  for (int s = 0; s < 64; ++s) qacc[s] = 0.f;

  {
    const int r = tid & 31, db = tid >> 5;
    const float4* src = reinterpret_cast<const float4*>(emb + (size_t)(n0 + r) * ND + db * 64);
    #pragma unroll
    for (int s = 0; s < 16; ++s) {
      float4 v = src[s];
      int d = db * 64 + s * 4;
      resT[d+0][r] = v.x; resT[d+1][r] = v.y; resT[d+2][r] = v.z; resT[d+3][r] = v.w;
    }
  }
  __syncthreads();

  const int c0l = cg * 8;
  const int swm = (c0l >> 6) << 2;
  const int off0 = c0l ^ swm;
  const int off1 = (c0l + 4) ^ swm;

  for (int q = 0; q < NQ; ++q) {
    const float* cbq = cbg + (size_t)q * NC * ND;
    float bd1[8], bd2[8]; int bi1[8], bi2[8];
    #pragma unroll
    for (int j = 0; j < 8; ++j) { bd1[j]=INFINITY; bd2[j]=INFINITY; bi1[j]=0x7fffffff; bi2[j]=0x7fffffff; }

    for (int cp = 0; cp < 2; ++cp) {
      float acc[8][8];
      #pragma unroll
      for (int a = 0; a < 8; ++a)
        #pragma unroll
        for (int b = 0; b < 8; ++b) acc[a][b] = 0.f;

      for (int kc = 0; kc < ND / BK; ++kc) {
        __syncthreads();
        {
          const int half = tid & 1;
          const int k0 = half * 16;
          #pragma unroll
          for (int it = 0; it < 4; ++it) {
            const int c = (tid >> 1) + it * 128;
            const int pc = c ^ ((c >> 6) << 2);
            const float4* src = reinterpret_cast<const float4*>(
                cbq + (size_t)(cp * CP + c) * ND + kc * BK + half * 16);
            float4 v0 = src[0], v1 = src[1], v2 = src[2], v3 = src[3];
            cc[k0+ 0][pc]=v0.x; cc[k0+ 1][pc]=v0.y; cc[k0+ 2][pc]=v0.z; cc[k0+ 3][pc]=v0.w;
            cc[k0+ 4][pc]=v1.x; cc[k0+ 5][pc]=v1.y; cc[k0+ 6][pc]=v1.z; cc[k0+ 7][pc]=v1.w;
            cc[k0+ 8][pc]=v2.x; cc[k0+ 9][pc]=v2.y; cc[k0+10][pc]=v2.z; cc[k0+11][pc]=v2.w;
            cc[k0+12][pc]=v3.x; cc[k0+13][pc]=v3.y; cc[k0+14][pc]=v3.z; cc[k0+15][pc]=v3.w;
          }
        }
        __syncthreads();

        float tmp[8][8];
        #pragma unroll
        for (int a = 0; a < 8; ++a)
          #pragma unroll
          for (int b = 0; b < 8; ++b) tmp[a][b] = 0.f;

        #pragma unroll
        for (int kk = 0; kk < BK; ++kk) {
          const float4* rp = reinterpret_cast<const float4*>(&resT[kc * BK + kk][rg * 8]);
          float4 r0 = rp[0], r1 = rp[1];
          const float* ccrow = &cc[kk][0];
          float4 c0 = *reinterpret_cast<const float4*>(ccrow + off0);
          float4 c1 = *reinterpret_cast<const float4*>(ccrow + off1);
          float rv[8] = {r0.x, r0.y, r0.z, r0.w, r1.x, r1.y, r1.z, r1.w};
          float cv[8] = {c0.x, c0.y, c0.z, c0.w, c1.x, c1.y, c1.z, c1.w};
          #pragma unroll
          for (int a = 0; a < 8; ++a)
            #pragma unroll
            for (int b = 0; b < 8; ++b)
              tmp[a][b] = fmaf(rv[a], cv[b], tmp[a][b]);
        }
        #pragma unroll
        for (int a = 0; a < 8; ++a)
          #pragma unroll
          for (int b = 0; b < 8; ++b) acc[a][b] += tmp[a][b];
      }

      const float4* qp = reinterpret_cast<const float4*>(cbsq + q * NC + cp * CP + cg * 8);
      float4 s0 = qp[0], s1 = qp[1];
      float sqv[8] = {s0.x, s0.y, s0.z, s0.w, s1.x, s1.y, s1.z, s1.w};
      #pragma unroll
      for (int r = 0; r < 8; ++r) {
        float d1 = INFINITY, d2 = INFINITY; int i1 = 0x7fffffff, i2 = 0x7fffffff;
        #pragma unroll
        for (int j = 0; j < 8; ++j) {
          float dd = sqv[j] - 2.0f * acc[r][j];
          merge_in(d1, i1, d2, i2, dd, cp * CP + cg * 8 + j);
        }
        #pragma unroll
        for (int m = 1; m < 64; m <<= 1) {
          float od1 = __shfl_xor(d1, m, 64), od2 = __shfl_xor(d2, m, 64);
          int oi1 = __shfl_xor(i1, m, 64), oi2 = __shfl_xor(i2, m, 64);
          merge_in(d1, i1, d2, i2, od1, oi1);
          merge_in(d1, i1, d2, i2, od2, oi2);
        }
        merge_in(bd1[r], bi1[r], bd2[r], bi2[r], d1, i1);
        merge_in(bd1[r], bi1[r], bd2[r], bi2[r], d2, i2);
      }
    }

    #pragma unroll 1
    for (int r = 0; r < 8; ++r) {
      int fi = bi1[r];
      if (bd2[r] - bd1[r] < TAU) {
        const int row = rg * 8 + r;
        const int ia = bi1[r], ib = bi2[r];
        double da = 0.0, db2 = 0.0;
        #pragma unroll 1
        for (int t = 0; t < 2; ++t) {
          const int cidx = t ? ib : ia;
          const float* cr = cbq + (size_t)cidx * ND;
          double dot = 0.0, ss = 0.0;
          #pragma unroll
          for (int u = 0; u < 8; ++u) {
            int k = lane * 8 + u;
            double cvv = (double)cr[k];
            double rvv = (double)resT[k][row];
            dot += cvv * rvv; ss += cvv * cvv;
          }
          #pragma unroll
          for (int m = 1; m < 64; m <<= 1) { dot += __shfl_xor(dot, m, 64); ss += __shfl_xor(ss, m, 64); }
          double dd = ss - 2.0 * dot;
          if (t) db2 = dd; else da = dd;
        }
        if (db2 < da || (db2 == da && ib < ia)) fi = ib;
      }
      fi = fi < 0 ? 0 : (fi > NC - 1 ? NC - 1 : fi);
      if (lane == 0) {
        idx_sh[rg * 8 + r] = fi;
        outf[QOFF + (size_t)(n0 + rg * 8 + r) * NQ + q] = (float)fi;
      }
    }
    __syncthreads();

    {
      const int r = tid & 31, db = tid >> 5;
      const float* crow = cbq + (size_t)idx_sh[r] * ND;
      float ls = 0.f;
      #pragma unroll
      for (int s = 0; s < 64; ++s) {
        int d = db * 64 + s;
        float cv = crow[d];
        float nv = resT[d][r] - cv;
        resT[d][r] = nv;
        qacc[s] += cv;
        ls += nv * nv;
      }
      #pragma unroll
      for (int m = 1; m < 64; m <<= 1) ls += __shfl_xor(ls, m, 64);
      if (lane == 0) wred[wv] = ls;
    }
    __syncthreads();
    if (tid == 0) lossws[blockIdx.x * NQ + q] = wred[0] + wred[1] + wred[2] + wred[3];
    __syncthreads();
  }

  {
    const int r = tid & 31, db = tid >> 5;
    #pragma unroll
    for (int g = 0; g < 16; ++g) {
      float4 w2;
      w2.x = qacc[g*4+0]; w2.y = qacc[g*4+1]; w2.z = qacc[g*4+2]; w2.w = qacc[g*4+3];
      *reinterpret_cast<float4*>(outf + (size_t)(n0 + r) * ND + db * 64 + g * 4) = w2;
    }
  }
}

__global__ __launch_bounds__(256) void loss_kernel(const float* __restrict__ lossws,
                                                   int n, float* __restrict__ outf) {
  __shared__ float red[256];
  const int tid = threadIdx.x;
  float s = 0.f;
  for (int i = tid; i < n; i += 256) s += lossws[i];
  red[tid] = s;
  __syncthreads();
  for (int w = 128; w > 0; w >>= 1) {
    if (tid < w) red[tid] += red[tid + w];
    __syncthreads();
  }
  if (tid == 0) outf[QOFF + (size_t)NROWTOT * NQ] = red[0] / 16777216.0f;
}

extern "C" void kernel_launch(void* const* d_in, const int* in_sizes, int n_in,
                              void* d_out, int out_size, void* d_ws, size_t ws_size,
                              hipStream_t stream) {
  (void)in_sizes; (void)n_in; (void)out_size;
  const float* emb = (const float*)d_in[0];
  const float* cbg = (const float*)d_in[1];
  float* wsf = (float*)d_ws;
  float* outf = (float*)d_out;

  cbsq_kernel<<<256, 256, 0, stream>>>(cbg, wsf);

  if (ws_size >= (size_t)18 * 1024 * 1024) {
    unsigned short* Bh = (unsigned short*)((char*)d_ws + 65536);
    unsigned short* Bl = Bh + 4194304;
    fmt_kernel<<<2048, 256, 0, stream>>>(cbg, Bh, Bl);
    rvq_mfma<<<512, 1024, 0, stream>>>(emb, cbg, wsf, wsf + 8192, Bh, Bl, outf);
    loss_kernel<<<1, 256, 0, stream>>>(wsf + 8192, 4096, outf);
  } else {
    rvq_fb<<<1024, 256, 0, stream>>>(emb, cbg, wsf, wsf + 8192, outf);
    loss_kernel<<<1, 256, 0, stream>>>(wsf + 8192, 8192, outf);
  }
}